// Round 9
// baseline (3252.065 us; speedup 1.0000x reference)
//
#include <hip/hip_runtime.h>
#include <math.h>

#define VOCABSZ 32000
#define EMBD 512
#define HIDD 512
#define BSZ 32
#define TLEN 32
#define G4 2048
#define NGRP 1000            // vocab col-groups of 32
#define PSTRIDE 8192         // part SoA stride (32 rows * 256 slots)
#define NLB 250              // logits blocks

using bf16x8 = __attribute__((ext_vector_type(8))) short;
using f32x16 = __attribute__((ext_vector_type(16))) float;

__device__ __forceinline__ float sigmoidf_(float x) { return 1.f / (1.f + expf(-x)); }
__device__ __forceinline__ unsigned short f2bf(float f) {
    unsigned u = __float_as_uint(f);
    return (unsigned short)((u + 0x7fffu + ((u >> 16) & 1u)) >> 16);   // RNE
}

// ---------------------------------------------------------------------------
// init: h <- x, c <- 0, inp <- emb[START], ce_acc <- 0, counters <- 0, probe
// ---------------------------------------------------------------------------
__global__ void init_kernel(const float* __restrict__ x,
                            const float* __restrict__ emb,
                            const void* __restrict__ coin,
                            float* __restrict__ h, float* __restrict__ c,
                            float* __restrict__ inp, float* __restrict__ ce_acc,
                            int* __restrict__ flag, int* __restrict__ counters) {
    int tid = threadIdx.x;
    if (tid == 0) {
        // coin dtype probe: uint8 bools pack to words like 0x00010001 (>1)
        const unsigned int* cw = (const unsigned int*)coin;
        int f = 0;
        for (int i = 0; i < 256; ++i) if (cw[i] > 1u) f = 1;
        *flag = f;
    }
    if (tid < 32) ce_acc[tid] = 0.f;
    if (tid < 33) counters[tid] = 0;
    for (int i = tid; i < BSZ * HIDD; i += blockDim.x) {
        h[i] = x[i];
        c[i] = 0.f;
        inp[i] = emb[EMBD + (i & (EMBD - 1))];   // START = 1
    }
}

// ---------------------------------------------------------------------------
// wot_prep: Wo [512][32000] fp32 -> bf16 in MFMA B-fragment order (as R8):
//   wot8[(g*32 + kt)*64 + lane] = { Wo[kt*16 + (lane>>5)*8 + j][g*32 + (lane&31)] }
// ---------------------------------------------------------------------------
__global__ __launch_bounds__(256) void wot_prep_kernel(
    const float* __restrict__ Wo, unsigned short* __restrict__ wot) {
    __shared__ unsigned short s[512 * 32];     // [k][col] 32 KB
    int g = blockIdx.x;
    int tid = threadIdx.x;
    int col = tid & 31;
    int k0 = tid >> 5;
    for (int kk = k0; kk < 512; kk += 8)
        s[kk * 32 + col] = f2bf(Wo[(size_t)kk * VOCABSZ + g * 32 + col]);
    __syncthreads();
    bf16x8* out8 = (bf16x8*)wot;
    for (int f = tid; f < 2048; f += 256) {
        int kt = f >> 6, lane = f & 63;
        int kb = kt * 16 + ((lane >> 5) << 3);
        int c = lane & 31;
        bf16x8 v;
        #pragma unroll
        for (int j = 0; j < 8; ++j) v[j] = (short)s[(kb + j) * 32 + c];
        out8[(size_t)g * 2048 + f] = v;
    }
}

// ---------------------------------------------------------------------------
// cell_fused: 64 blocks x 512 thr. Block owns 8 hidden cols (32 gate cols).
// Thread decode: colq = tid&7 (gate g=colq>>1, quad q=colq&1 -> 4 cols),
//                rowg = (tid>>3)&7 (4 rows), ksl = tid>>6 (8 K-slices).
// 4 chunks of 256 k staged row-major in LDS (pad 261: rr-stride bank 5,
// rowg-stride bank 20 -> conflict-free broadcast). K-slice partials combined
// via sg LDS, then gate activation fused (256 tasks), h written fp32 + bf16.
// ---------------------------------------------------------------------------
__global__ __launch_bounds__(512) void cell_fused_kernel(
    const float* __restrict__ inp, const float* __restrict__ Wi,
    const float* __restrict__ Wh, const float* __restrict__ hsrc,
    const float* __restrict__ bias, float* __restrict__ cst,
    float* __restrict__ hdst, unsigned short* __restrict__ hbf) {
    __shared__ float s_x[32][261];      // 33.4 KB chunk [row][k]
    __shared__ float sg[8][32][32];     // 32 KB  [ksl][row][gatecol]
    int tid = threadIdx.x;
    int cb = blockIdx.x;
    int colq = tid & 7;
    int rowg = (tid >> 3) & 7;
    int ksl = tid >> 6;
    int g = colq >> 1, q = colq & 1;
    int col = g * 512 + cb * 8 + q * 4;

    float acc[4][4] = {{0.f,0.f,0.f,0.f},{0.f,0.f,0.f,0.f},
                       {0.f,0.f,0.f,0.f},{0.f,0.f,0.f,0.f}};

    for (int ch = 0; ch < 4; ++ch) {
        int kb = ch * 256;
        const float* Xb = (kb < 512) ? inp : hsrc;
        int ko = (kb < 512) ? kb : (kb - 512);
        #pragma unroll
        for (int it = 0; it < 4; ++it) {
            int i4 = it * 512 + tid;            // 2048 float4 = 32r x 256k
            int r = i4 >> 6;
            int kk = (i4 & 63) << 2;
            float4 v = *(const float4*)&Xb[r * HIDD + ko + kk];
            s_x[r][kk] = v.x; s_x[r][kk + 1] = v.y;
            s_x[r][kk + 2] = v.z; s_x[r][kk + 3] = v.w;
        }
        __syncthreads();
        const float* W = (kb < 512) ? (Wi + (size_t)kb * G4)
                                    : (Wh + (size_t)(kb - 512) * G4);
        int k0 = ksl * 32;
        #pragma unroll 4
        for (int kk = k0; kk < k0 + 32; ++kk) {
            float4 w = *(const float4*)&W[(size_t)kk * G4 + col];
            float x0 = s_x[rowg * 4 + 0][kk];
            float x1 = s_x[rowg * 4 + 1][kk];
            float x2 = s_x[rowg * 4 + 2][kk];
            float x3 = s_x[rowg * 4 + 3][kk];
            acc[0][0] += x0 * w.x; acc[0][1] += x0 * w.y;
            acc[0][2] += x0 * w.z; acc[0][3] += x0 * w.w;
            acc[1][0] += x1 * w.x; acc[1][1] += x1 * w.y;
            acc[1][2] += x1 * w.z; acc[1][3] += x1 * w.w;
            acc[2][0] += x2 * w.x; acc[2][1] += x2 * w.y;
            acc[2][2] += x2 * w.z; acc[2][3] += x2 * w.w;
            acc[3][0] += x3 * w.x; acc[3][1] += x3 * w.y;
            acc[3][2] += x3 * w.z; acc[3][3] += x3 * w.w;
        }
        __syncthreads();
    }
    #pragma unroll
    for (int rr = 0; rr < 4; ++rr)
        #pragma unroll
        for (int cc = 0; cc < 4; ++cc)
            sg[ksl][rowg * 4 + rr][g * 8 + q * 4 + cc] = acc[rr][cc];
    __syncthreads();
    if (tid < 256) {
        int r = tid >> 3, jj = tid & 7;
        int jh = cb * 8 + jj;
        float i_ = bias[jh], f_ = bias[jh + 512];
        float g_ = bias[jh + 1024], o_ = bias[jh + 1536];
        #pragma unroll
        for (int s2 = 0; s2 < 8; ++s2) {
            i_ += sg[s2][r][jj];
            f_ += sg[s2][r][jj + 8];
            g_ += sg[s2][r][jj + 16];
            o_ += sg[s2][r][jj + 24];
        }
        int idx = r * HIDD + jh;
        float ci = cst[idx];
        float cn = sigmoidf_(f_) * ci + sigmoidf_(i_) * tanhf(g_);
        float hn = sigmoidf_(o_) * tanhf(cn);
        cst[idx] = cn;
        hdst[idx] = hn;
        hbf[idx] = f2bf(hn);
    }
}

// ---------------------------------------------------------------------------
// logits_tail: 250 blocks x 256 thr (4 waves). Wave = 32 vocab cols, K=512
// via 2x16 mfma_f32_32x32x16_bf16 (split acc -> chain halved). Partials as
// R8. Then last-block-done tail: __threadfence (release) -> atomicAdd counter
// -> last block __threadfence (acquire) + combine 250 partials, CE accum,
// token select, emb gather -> inp; at t==32 writes final out.
// C/D layout: col = lane&31, row = (reg&3) + 8*(reg>>2) + 4*(lane>>5).
// ---------------------------------------------------------------------------
__global__ __launch_bounds__(256) void logits_tail_kernel(
    const unsigned short* __restrict__ wot, const unsigned short* __restrict__ h_bf,
    const float* __restrict__ bo, const int* __restrict__ labels,
    const void* __restrict__ coin, const int* __restrict__ flag,
    const float* __restrict__ emb, float* part, int* counters,
    float* ce_acc, float* inp, float* out, int t) {
    __shared__ __align__(16) unsigned short s_h[16384];   // 32 KB frag-order
    __shared__ int s_lab[32];
    __shared__ float s_pm[4][32], s_ps[4][32], s_pl[4][32], s_pst[4][32];
    __shared__ int s_pi[4][32];
    __shared__ int s_last;
    __shared__ float s_ce2[32];
    __shared__ int s_tok2[32];
    int tid = threadIdx.x;
    int lane = tid & 63, wv = tid >> 6;
    int ls = (t < 32) ? t : 0;

    for (int f = tid; f < 2048; f += 256) {
        int kt = f >> 6, ln = f & 63;
        int row = ln & 31, kb = kt * 16 + ((ln >> 5) << 3);
        *(bf16x8*)&s_h[f * 8] = *(const bf16x8*)&h_bf[row * 512 + kb];
    }
    if (tid < 32) s_lab[tid] = labels[tid * TLEN + ls];
    __syncthreads();

    int g = blockIdx.x * 4 + wv;                 // col-group 0..999
    const bf16x8* wp = (const bf16x8*)wot + (size_t)g * 2048 + lane;
    const bf16x8* sh8 = (const bf16x8*)s_h;

    f32x16 acc0 = {}, acc1 = {};
    #pragma unroll 4
    for (int kt = 0; kt < 16; ++kt) {
        acc0 = __builtin_amdgcn_mfma_f32_32x32x16_bf16(
            sh8[kt * 64 + lane], wp[kt * 64], acc0, 0, 0, 0);
        acc1 = __builtin_amdgcn_mfma_f32_32x32x16_bf16(
            sh8[(kt + 16) * 64 + lane], wp[(kt + 16) * 64], acc1, 0, 0, 0);
    }

    int half = lane >> 5;
    int colw = lane & 31;
    int col = g * 32 + colw;
    float bq = bo[col];

    #pragma unroll
    for (int reg = 0; reg < 16; ++reg) {
        int row = (reg & 3) + 8 * (reg >> 2) + 4 * half;
        float v = acc0[reg] + acc1[reg] + bq;
        float m = v; int mi = col;
        #pragma unroll
        for (int d = 1; d < 32; d <<= 1) {
            float om = __shfl_xor(m, d);
            int omi = __shfl_xor(mi, d);
            if (om > m || (om == m && omi < mi)) { m = om; mi = omi; }
        }
        float e = expf(v - m), ssum = e;
        #pragma unroll
        for (int d = 1; d < 32; d <<= 1) ssum += __shfl_xor(ssum, d);
        int labc = s_lab[row];
        float lv = __shfl(v, (labc & 31) + (half << 5));
        if ((labc >> 5) != g) lv = -INFINITY;
        float sv = __shfl(v, 2 + (half << 5));   // STOP = 2
        if (g != 0) sv = -INFINITY;
        if (colw == 0) {
            s_pm[wv][row] = m; s_ps[wv][row] = ssum; s_pi[wv][row] = mi;
            s_pl[wv][row] = lv; s_pst[wv][row] = sv;
        }
    }
    __syncthreads();

    if (tid < 32) {
        int row = tid;
        float M = s_pm[0][row], S = s_ps[0][row];
        int MI = s_pi[0][row];
        float L = s_pl[0][row], ST = s_pst[0][row];
        #pragma unroll
        for (int w = 1; w < 4; ++w) {
            float pm = s_pm[w][row], ps = s_ps[w][row];
            int pi = s_pi[w][row];
            float nM = fmaxf(M, pm);
            S = S * expf(M - nM) + ps * expf(pm - nM);
            if (pm > M || (pm == M && pi < MI)) MI = pi;
            M = nM;
            L = fmaxf(L, s_pl[w][row]);
            ST = fmaxf(ST, s_pst[w][row]);
        }
        int e0 = row * 256 + blockIdx.x;
        part[e0] = M;
        part[PSTRIDE + e0] = S;
        part[2 * PSTRIDE + e0] = __int_as_float(MI);
        part[3 * PSTRIDE + e0] = L;
        part[4 * PSTRIDE + e0] = ST;
    }
    __threadfence();                      // release part writes device-wide
    __syncthreads();
    if (tid == 0) s_last = (atomicAdd(&counters[t], 1) == NLB - 1);
    __syncthreads();
    if (!s_last) return;
    __threadfence();                      // acquire: see all blocks' partials

    // -------- tail reduce (this block only) --------
    int is_final = (t == 32);
    for (int rr = 0; rr < 8; ++rr) {
        int row = rr * 4 + wv;
        // -3e38 (not -inf) so inactive merges never make 0*exp(nan)
        float M = -3.0e38f, S = 0.f, L = -INFINITY, ST = -INFINITY;
        int MI = 0;
        for (int ib = lane; ib < NLB; ib += 64) {
            int e = row * 256 + ib;
            float pm = part[e], ps = part[PSTRIDE + e];
            int pi = __float_as_int(part[2 * PSTRIDE + e]);
            float nM = fmaxf(M, pm);
            S = S * expf(M - nM) + ps * expf(pm - nM);
            if (pm > M || (pm == M && pi < MI)) MI = pi;
            M = nM;
            L = fmaxf(L, part[3 * PSTRIDE + e]);
            ST = fmaxf(ST, part[4 * PSTRIDE + e]);
        }
        #pragma unroll
        for (int d = 1; d < 64; d <<= 1) {
            float oM = __shfl_xor(M, d), oS = __shfl_xor(S, d);
            int oI = __shfl_xor(MI, d);
            float oL = __shfl_xor(L, d), oST = __shfl_xor(ST, d);
            float nM = fmaxf(M, oM);
            S = S * expf(M - nM) + oS * expf(oM - nM);
            if (oM > M || (oM == M && oI < MI)) MI = oI;
            M = nM;
            L = fmaxf(L, oL);
            ST = fmaxf(ST, oST);
        }
        if (lane == 0) {
            float logZ = M + logf(S);
            float ce = logZ - (is_final ? ST : L);
            float nv = ce_acc[row] + ce;
            ce_acc[row] = nv;
            s_ce2[row] = nv;
            if (!is_final) {
                int lab = labels[row * TLEN + t];
                int cn = (*flag) ? (int)((const unsigned char*)coin)[row * TLEN + t]
                                 : ((const int*)coin)[row * TLEN + t];
                s_tok2[row] = cn ? MI : lab;
            }
        }
    }
    __syncthreads();
    if (!is_final) {
        #pragma unroll
        for (int it = 0; it < 16; ++it) {
            int i4 = it * 256 + tid;          // 4096 float4 = 32r x 512
            int r = i4 >> 7;
            int d = (i4 & 127) << 2;
            *(float4*)&inp[r * EMBD + d] =
                *(const float4*)&emb[(size_t)s_tok2[r] * EMBD + d];
        }
    } else if (tid == 0) {
        float tot = 0.f;
        for (int r = 0; r < 32; ++r) tot += s_ce2[r];
        *out = tot / 32.f;
    }
}

// ===========================================================================
extern "C" void kernel_launch(void* const* d_in, const int* in_sizes, int n_in,
                              void* d_out, int out_size, void* d_ws, size_t ws_size,
                              hipStream_t stream) {
    const float* x      = (const float*)d_in[0];
    const int*   labels = (const int*)  d_in[1];
    const void*  coin   =               d_in[2];
    const float* emb    = (const float*)d_in[3];
    const float* Wi     = (const float*)d_in[4];
    const float* Wh     = (const float*)d_in[5];
    const float* b      = (const float*)d_in[6];
    const float* Wo     = (const float*)d_in[7];
    const float* bo     = (const float*)d_in[8];

    float* ws     = (float*)d_ws;
    float* hA     = ws;                        // 16384
    float* hB     = ws + 16384;                // 16384
    float* cst    = ws + 32768;                // 16384
    float* inp    = ws + 49152;                // 16384
    unsigned short* h_bf = (unsigned short*)(ws + 65536);   // 8192 floats
    float* part   = ws + 73728;                // 5*8192 = 40960
    float* ce_acc = ws + 114688;               // 32
    int*   flag   = (int*)(ws + 114720);       // 1
    int*   cnts   = (int*)(ws + 114721);       // 33
    unsigned short* wot = (unsigned short*)(ws + 114756);   // 8192000 floats
    float* outp   = (float*)d_out;

    wot_prep_kernel<<<NGRP, 256, 0, stream>>>(Wo, wot);
    init_kernel<<<1, 256, 0, stream>>>(x, emb, coin, hA, cst, inp, ce_acc, flag, cnts);

    float* hsrc = hA;
    float* hdst = hB;
    for (int t = 0; t < 33; ++t) {
        cell_fused_kernel<<<64, 512, 0, stream>>>(inp, Wi, Wh, hsrc, b, cst,
                                                  hdst, h_bf);
        logits_tail_kernel<<<NLB, 256, 0, stream>>>(wot, h_bf, bo, labels, coin,
                                                    flag, emb, part, cnts,
                                                    ce_acc, inp, outp, t);
        float* tmp = hsrc; hsrc = hdst; hdst = tmp;
    }
}

// Round 10
// 3045.439 us; speedup vs baseline: 1.0678x; 1.0678x over previous
//
#include <hip/hip_runtime.h>
#include <math.h>

#define VOCABSZ 32000
#define EMBD 512
#define HIDD 512
#define BSZ 32
#define TLEN 32
#define G4 2048
#define NGRP 1000            // vocab col-groups of 32 (also logits grid)
#define PS2 32768            // part SoA stride (32 rows * 1024 slots)

using bf16x8 = __attribute__((ext_vector_type(8))) short;
using f32x16 = __attribute__((ext_vector_type(16))) float;

__device__ __forceinline__ float sigmoidf_(float x) { return 1.f / (1.f + expf(-x)); }
__device__ __forceinline__ unsigned short f2bf(float f) {
    unsigned u = __float_as_uint(f);
    return (unsigned short)((u + 0x7fffu + ((u >> 16) & 1u)) >> 16);   // RNE
}

// ---------------------------------------------------------------------------
// init2: h <- x, c <- 0, ce_acc <- 0, coin dtype probe
// ---------------------------------------------------------------------------
__global__ void init2_kernel(const float* __restrict__ x,
                             const void* __restrict__ coin,
                             float* __restrict__ h, float* __restrict__ c,
                             float* __restrict__ ce_acc, int* __restrict__ flag) {
    int tid = threadIdx.x;
    if (tid == 0) {
        // coin dtype probe: uint8 bools pack to words like 0x00010001 (>1)
        const unsigned int* cw = (const unsigned int*)coin;
        int f = 0;
        for (int i = 0; i < 256; ++i) if (cw[i] > 1u) f = 1;
        *flag = f;
    }
    if (tid < 32) ce_acc[tid] = 0.f;
    for (int i = tid; i < BSZ * HIDD; i += blockDim.x) {
        h[i] = x[i];
        c[i] = 0.f;
    }
}

// ---------------------------------------------------------------------------
// wot_prep: Wo [512][32000] fp32 -> bf16 in MFMA B-fragment order (R8-proven):
//   wot8[(g*32 + kt)*64 + lane] = { Wo[kt*16 + (lane>>5)*8 + j][g*32 + (lane&31)] }
// ---------------------------------------------------------------------------
__global__ __launch_bounds__(256) void wot_prep_kernel(
    const float* __restrict__ Wo, unsigned short* __restrict__ wot) {
    __shared__ unsigned short s[512 * 32];     // [k][col] 32 KB
    int g = blockIdx.x;
    int tid = threadIdx.x;
    int col = tid & 31;
    int k0 = tid >> 5;
    for (int kk = k0; kk < 512; kk += 8)
        s[kk * 32 + col] = f2bf(Wo[(size_t)kk * VOCABSZ + g * 32 + col]);
    __syncthreads();
    bf16x8* out8 = (bf16x8*)wot;
    for (int f = tid; f < 2048; f += 256) {
        int kt = f >> 6, lane = f & 63;
        int kb = kt * 16 + ((lane >> 5) << 3);
        int c = lane & 31;
        bf16x8 v;
        #pragma unroll
        for (int j = 0; j < 8; ++j) v[j] = (short)s[(kb + j) * 32 + c];
        out8[(size_t)g * 2048 + f] = v;
    }
}

// ---------------------------------------------------------------------------
// cell_fused2: 64 blocks x 512 thr. Per step t:
//  PHASE A (t>0): redundant token-reduce from part (1000 slots/row): 8 slots
//    x 32 rows (tid<256); block 0 additionally merges M/S/L online and
//    accumulates CE for step t-1 into ce_acc. t==0: tok = START = 1.
//  PHASE B: gate GEMM (R9-proven): 4 chunks of 256 k staged in LDS
//    ([32][261] pad), X gathered inline from emb[s_tok[r]] (k<512) or hsrc;
//    8 K-slices x 8x8 col-row threads; sg-combine; gate math; h fp32+bf16.
// ---------------------------------------------------------------------------
__global__ __launch_bounds__(512) void cell_fused2_kernel(
    const float* __restrict__ emb, const int* __restrict__ labels,
    const void* __restrict__ coin, const int* __restrict__ flag,
    const float* __restrict__ Wi, const float* __restrict__ Wh,
    const float* __restrict__ hsrc, const float* __restrict__ bias,
    float* __restrict__ cst, float* __restrict__ hdst,
    unsigned short* __restrict__ hbf, const float* __restrict__ part,
    float* __restrict__ ce_acc, int t) {
    __shared__ float s_x[32][261];      // 33.4 KB chunk [row][k]
    __shared__ float sg[8][32][32];     // 32 KB  [ksl][row][gatecol]
    __shared__ int s_tok[32];
    int tid = threadIdx.x;
    int cb = blockIdx.x;

    // ---- PHASE A: tokens (+CE in block 0) ----
    if (t == 0) {
        if (tid < 32) s_tok[tid] = 1;            // START
    } else if (tid < 256) {
        int row = tid >> 3, slot = tid & 7;
        int tm1 = t - 1;
        float m = -3.0e38f; int mi = 0;
        for (int ib = slot; ib < NGRP; ib += 8) {
            int e = row * 1024 + ib;
            float pm = part[e];
            int pi = __float_as_int(part[2 * PS2 + e]);
            if (pm > m || (pm == m && pi < mi)) { m = pm; mi = pi; }
        }
        #pragma unroll
        for (int d = 1; d < 8; d <<= 1) {
            float om = __shfl_xor(m, d);
            int omi = __shfl_xor(mi, d);
            if (om > m || (om == m && omi < mi)) { m = om; mi = omi; }
        }
        if (slot == 0) {
            int lab = labels[row * TLEN + tm1];
            int cn = (*flag) ? (int)((const unsigned char*)coin)[row * TLEN + tm1]
                             : ((const int*)coin)[row * TLEN + tm1];
            s_tok[row] = cn ? mi : lab;
        }
        if (cb == 0) {
            // CE for step t-1 (label logit; t-1 <= 31 always)
            float M = -3.0e38f, S = 0.f, L = -INFINITY;
            for (int ib = slot; ib < NGRP; ib += 8) {
                int e = row * 1024 + ib;
                float pm = part[e], ps = part[PS2 + e];
                float nM = fmaxf(M, pm);
                S = S * expf(M - nM) + ps * expf(pm - nM);
                M = nM;
                L = fmaxf(L, part[3 * PS2 + e]);
            }
            #pragma unroll
            for (int d = 1; d < 8; d <<= 1) {
                float oM = __shfl_xor(M, d), oS = __shfl_xor(S, d);
                float nM = fmaxf(M, oM);
                S = S * expf(M - nM) + oS * expf(oM - nM);
                M = nM;
                L = fmaxf(L, __shfl_xor(L, d));
            }
            if (slot == 0) ce_acc[row] += (M + logf(S)) - L;
        }
    }
    __syncthreads();

    // ---- PHASE B: gate GEMM ----
    int colq = tid & 7;
    int rowg = (tid >> 3) & 7;
    int ksl = tid >> 6;
    int g = colq >> 1, q = colq & 1;
    int col = g * 512 + cb * 8 + q * 4;

    float acc[4][4] = {{0.f,0.f,0.f,0.f},{0.f,0.f,0.f,0.f},
                       {0.f,0.f,0.f,0.f},{0.f,0.f,0.f,0.f}};

    for (int ch = 0; ch < 4; ++ch) {
        int kb = ch * 256;
        int ko = (kb < 512) ? kb : (kb - 512);
        #pragma unroll
        for (int it = 0; it < 4; ++it) {
            int i4 = it * 512 + tid;            // 2048 float4 = 32r x 256k
            int r = i4 >> 6;
            int kk = (i4 & 63) << 2;
            float4 v;
            if (kb < 512)
                v = *(const float4*)&emb[(size_t)s_tok[r] * EMBD + ko + kk];
            else
                v = *(const float4*)&hsrc[r * HIDD + ko + kk];
            s_x[r][kk] = v.x; s_x[r][kk + 1] = v.y;
            s_x[r][kk + 2] = v.z; s_x[r][kk + 3] = v.w;
        }
        __syncthreads();
        const float* W = (kb < 512) ? (Wi + (size_t)kb * G4)
                                    : (Wh + (size_t)(kb - 512) * G4);
        int k0 = ksl * 32;
        #pragma unroll 4
        for (int kk = k0; kk < k0 + 32; ++kk) {
            float4 w = *(const float4*)&W[(size_t)kk * G4 + col];
            float x0 = s_x[rowg * 4 + 0][kk];
            float x1 = s_x[rowg * 4 + 1][kk];
            float x2 = s_x[rowg * 4 + 2][kk];
            float x3 = s_x[rowg * 4 + 3][kk];
            acc[0][0] += x0 * w.x; acc[0][1] += x0 * w.y;
            acc[0][2] += x0 * w.z; acc[0][3] += x0 * w.w;
            acc[1][0] += x1 * w.x; acc[1][1] += x1 * w.y;
            acc[1][2] += x1 * w.z; acc[1][3] += x1 * w.w;
            acc[2][0] += x2 * w.x; acc[2][1] += x2 * w.y;
            acc[2][2] += x2 * w.z; acc[2][3] += x2 * w.w;
            acc[3][0] += x3 * w.x; acc[3][1] += x3 * w.y;
            acc[3][2] += x3 * w.z; acc[3][3] += x3 * w.w;
        }
        __syncthreads();
    }
    #pragma unroll
    for (int rr = 0; rr < 4; ++rr)
        #pragma unroll
        for (int cc = 0; cc < 4; ++cc)
            sg[ksl][rowg * 4 + rr][g * 8 + q * 4 + cc] = acc[rr][cc];
    __syncthreads();
    if (tid < 256) {
        int r = tid >> 3, jj = tid & 7;
        int jh = cb * 8 + jj;
        float i_ = bias[jh], f_ = bias[jh + 512];
        float g_ = bias[jh + 1024], o_ = bias[jh + 1536];
        #pragma unroll
        for (int s2 = 0; s2 < 8; ++s2) {
            i_ += sg[s2][r][jj];
            f_ += sg[s2][r][jj + 8];
            g_ += sg[s2][r][jj + 16];
            o_ += sg[s2][r][jj + 24];
        }
        int idx = r * HIDD + jh;
        float ci = cst[idx];
        float cn = sigmoidf_(f_) * ci + sigmoidf_(i_) * tanhf(g_);
        float hn = sigmoidf_(o_) * tanhf(cn);
        cst[idx] = cn;
        hdst[idx] = hn;
        hbf[idx] = f2bf(hn);
    }
}

// ---------------------------------------------------------------------------
// logits_v3: 1000 blocks x 64 thr (1 wave = 1 col-group of 32 vocab cols).
// No LDS, no barriers. A from global h_bf (natural order; lanes ln/ln+32
// read adjacent 16B), B from pre-swizzled wot (coalesced 1KB/wave, L2-hot).
// 2 split acc chains. Epilogue: in-wave softmax partials written directly
// to this wave's slot (part stride 1024).
// C/D layout: col = lane&31, row = (reg&3) + 8*(reg>>2) + 4*(lane>>5).
// ---------------------------------------------------------------------------
__global__ __launch_bounds__(64) void logits_v3_kernel(
    const unsigned short* __restrict__ wot, const unsigned short* __restrict__ h_bf,
    const float* __restrict__ bo, const int* __restrict__ labels,
    float* __restrict__ part, int t) {
    int lane = threadIdx.x;
    int g = blockIdx.x;
    int half = lane >> 5, colw = lane & 31;
    int ls = (t < 32) ? t : 0;

    const bf16x8* wp = (const bf16x8*)wot + (size_t)g * 2048 + lane;
    const bf16x8* hp = (const bf16x8*)h_bf + colw * 64 + half;   // + kt*2

    f32x16 acc0 = {}, acc1 = {};
    #pragma unroll 4
    for (int kt = 0; kt < 16; ++kt) {
        acc0 = __builtin_amdgcn_mfma_f32_32x32x16_bf16(
            hp[kt * 2], wp[kt * 64], acc0, 0, 0, 0);
        acc1 = __builtin_amdgcn_mfma_f32_32x32x16_bf16(
            hp[(kt + 16) * 2], wp[(kt + 16) * 64], acc1, 0, 0, 0);
    }

    int col = g * 32 + colw;
    float bq = bo[col];

    #pragma unroll
    for (int reg = 0; reg < 16; ++reg) {
        int row = (reg & 3) + 8 * (reg >> 2) + 4 * half;
        float v = acc0[reg] + acc1[reg] + bq;
        float m = v; int mi = col;
        #pragma unroll
        for (int d = 1; d < 32; d <<= 1) {
            float om = __shfl_xor(m, d);
            int omi = __shfl_xor(mi, d);
            if (om > m || (om == m && omi < mi)) { m = om; mi = omi; }
        }
        float e = expf(v - m), ssum = e;
        #pragma unroll
        for (int d = 1; d < 32; d <<= 1) ssum += __shfl_xor(ssum, d);
        int labc = labels[row * TLEN + ls];
        float lv = __shfl(v, (labc & 31) + (half << 5));
        if ((labc >> 5) != g) lv = -INFINITY;
        float sv = __shfl(v, 2 + (half << 5));   // STOP = 2
        if (g != 0) sv = -INFINITY;
        if (colw == 0) {
            int e0 = row * 1024 + g;
            part[e0] = m;
            part[PS2 + e0] = ssum;
            part[2 * PS2 + e0] = __int_as_float(mi);
            part[3 * PS2 + e0] = lv;
            part[4 * PS2 + e0] = sv;
        }
    }
}

// ---------------------------------------------------------------------------
// finalize2: reduce part(t=32) with STOP logit; out = (ce_acc + final)/32
// ---------------------------------------------------------------------------
__global__ __launch_bounds__(256) void finalize2_kernel(
    const float* __restrict__ part, const float* __restrict__ ce_acc,
    float* __restrict__ out) {
    __shared__ float s_ce[32];
    int tid = threadIdx.x;
    int row = tid >> 3, slot = tid & 7;
    float M = -3.0e38f, S = 0.f, ST = -INFINITY;
    for (int ib = slot; ib < NGRP; ib += 8) {
        int e = row * 1024 + ib;
        float pm = part[e], ps = part[PS2 + e];
        float nM = fmaxf(M, pm);
        S = S * expf(M - nM) + ps * expf(pm - nM);
        M = nM;
        ST = fmaxf(ST, part[4 * PS2 + e]);
    }
    #pragma unroll
    for (int d = 1; d < 8; d <<= 1) {
        float oM = __shfl_xor(M, d), oS = __shfl_xor(S, d);
        float nM = fmaxf(M, oM);
        S = S * expf(M - nM) + oS * expf(oM - nM);
        M = nM;
        ST = fmaxf(ST, __shfl_xor(ST, d));
    }
    if (slot == 0) s_ce[row] = ce_acc[row] + (M + logf(S)) - ST;
    __syncthreads();
    if (tid == 0) {
        float tot = 0.f;
        for (int r = 0; r < 32; ++r) tot += s_ce[r];
        *out = tot / 32.f;
    }
}

// ===========================================================================
extern "C" void kernel_launch(void* const* d_in, const int* in_sizes, int n_in,
                              void* d_out, int out_size, void* d_ws, size_t ws_size,
                              hipStream_t stream) {
    const float* x      = (const float*)d_in[0];
    const int*   labels = (const int*)  d_in[1];
    const void*  coin   =               d_in[2];
    const float* emb    = (const float*)d_in[3];
    const float* Wi     = (const float*)d_in[4];
    const float* Wh     = (const float*)d_in[5];
    const float* b      = (const float*)d_in[6];
    const float* Wo     = (const float*)d_in[7];
    const float* bo     = (const float*)d_in[8];

    float* ws     = (float*)d_ws;
    float* hA     = ws;                        // 16384
    float* hB     = ws + 16384;                // 16384
    float* cst    = ws + 32768;                // 16384
    unsigned short* h_bf = (unsigned short*)(ws + 49152);   // 8192 floats
    float* part   = ws + 57344;                // 5*32768 = 163840
    float* ce_acc = ws + 221184;               // 32
    int*   flag   = (int*)(ws + 221216);       // 1 (+pad)
    unsigned short* wot = (unsigned short*)(ws + 221248);   // 8192000 floats
    float* outp   = (float*)d_out;

    wot_prep_kernel<<<NGRP, 256, 0, stream>>>(Wo, wot);
    init2_kernel<<<1, 256, 0, stream>>>(x, coin, hA, cst, ce_acc, flag);

    float* hsrc = hA;
    float* hdst = hB;
    for (int t = 0; t < 33; ++t) {
        cell_fused2_kernel<<<64, 512, 0, stream>>>(emb, labels, coin, flag,
                                                   Wi, Wh, hsrc, b, cst, hdst,
                                                   h_bf, part, ce_acc, t);
        logits_v3_kernel<<<NGRP, 64, 0, stream>>>(wot, h_bf, bo, labels, part, t);
        float* tmp = hsrc; hsrc = hdst; hdst = tmp;
    }
    finalize2_kernel<<<1, 256, 0, stream>>>(part, ce_acc, outp);
}

// Round 11
// 1529.762 us; speedup vs baseline: 2.1259x; 1.9908x over previous
//
#include <hip/hip_runtime.h>
#include <math.h>

#define VOCABSZ 32000
#define EMBD 512
#define HIDD 512
#define BSZ 32
#define TLEN 32
#define G4 2048
#define NGRP 1000            // wot col-groups of 32
#define NLB 250              // logits blocks / partial slots
#define PSTRIDE 8192         // part SoA stride (32 rows * 256 slots)

using bf16x8 = __attribute__((ext_vector_type(8))) short;
using f32x16 = __attribute__((ext_vector_type(16))) float;

__device__ __forceinline__ float sigmoidf_(float x) { return 1.f / (1.f + expf(-x)); }
__device__ __forceinline__ unsigned short f2bf(float f) {
    unsigned u = __float_as_uint(f);
    return (unsigned short)((u + 0x7fffu + ((u >> 16) & 1u)) >> 16);   // RNE
}

// ---------------------------------------------------------------------------
// init3: cst <- 0, hA <- x (fallback), h_bf <- bf16(x), ce_acc <- 0, probe
// ---------------------------------------------------------------------------
__global__ void init3_kernel(const float* __restrict__ x,
                             const void* __restrict__ coin,
                             float* __restrict__ hA, float* __restrict__ c,
                             unsigned short* __restrict__ hbf,
                             float* __restrict__ ce_acc, int* __restrict__ flag) {
    int tid = threadIdx.x;
    if (tid == 0) {
        // coin dtype probe: uint8 bools pack to words like 0x00010001 (>1)
        const unsigned int* cw = (const unsigned int*)coin;
        int f = 0;
        for (int i = 0; i < 256; ++i) if (cw[i] > 1u) f = 1;
        *flag = f;
    }
    if (tid < 32) ce_acc[tid] = 0.f;
    for (int i = tid; i < BSZ * HIDD; i += blockDim.x) {
        float v = x[i];
        hA[i] = v;
        c[i] = 0.f;
        hbf[i] = f2bf(v);
    }
}

// ---------------------------------------------------------------------------
// wot_prep (R8-proven): Wo [512][32000] fp32 -> bf16 MFMA B-frag order:
//   wot8[(g*32 + kt)*64 + lane] = Wo[kt*16+(lane>>5)*8+j][g*32+(lane&31)]
// ---------------------------------------------------------------------------
__global__ __launch_bounds__(256) void wot_prep_kernel(
    const float* __restrict__ Wo, unsigned short* __restrict__ wot) {
    __shared__ unsigned short s[512 * 32];     // [k][col] 32 KB
    int g = blockIdx.x;
    int tid = threadIdx.x;
    int col = tid & 31;
    int k0 = tid >> 5;
    for (int kk = k0; kk < 512; kk += 8)
        s[kk * 32 + col] = f2bf(Wo[(size_t)kk * VOCABSZ + g * 32 + col]);
    __syncthreads();
    bf16x8* out8 = (bf16x8*)wot;
    for (int f = tid; f < 2048; f += 256) {
        int kt = f >> 6, lane = f & 63;
        int kb = kt * 16 + ((lane >> 5) << 3);
        int c = lane & 31;
        bf16x8 v;
        #pragma unroll
        for (int j = 0; j < 8; ++j) v[j] = (short)s[(kb + j) * 32 + c];
        out8[(size_t)g * 2048 + f] = v;
    }
}

// ---------------------------------------------------------------------------
// wcell_prep: Wi/Wh [512][2048] fp32 -> bf16 B-frag order, block-packed:
// block cb owns local cols lc=g*8+jj -> global col g*512 + cb*8 + jj.
//   wcell8[(cb*64 + kt)*64 + lane] = W[k][colmap], k = kt*16+(lane>>5)*8+j,
// kt<32 from Wi (k), kt>=32 from Wh (k-512). grid 128 = cb(64) x half(2).
// ---------------------------------------------------------------------------
__global__ __launch_bounds__(256) void wcell_prep_kernel(
    const float* __restrict__ Wi, const float* __restrict__ Wh,
    unsigned short* __restrict__ wcell) {
    __shared__ unsigned short s[512 * 32];     // [kl][lc] 32 KB
    int cb = blockIdx.x >> 1;
    int half = blockIdx.x & 1;
    const float* Wsrc = half ? Wh : Wi;
    int tid = threadIdx.x;
    int lc = tid & 31;
    int gcol = (lc >> 3) * 512 + cb * 8 + (lc & 7);
    int k0 = tid >> 5;
    for (int kl = k0; kl < 512; kl += 8)
        s[kl * 32 + lc] = f2bf(Wsrc[(size_t)kl * G4 + gcol]);
    __syncthreads();
    bf16x8* out8 = (bf16x8*)wcell;
    for (int f = tid; f < 2048; f += 256) {
        int ktl = f >> 6, lane = f & 63;
        int kb = ktl * 16 + ((lane >> 5) << 3);
        int c = lane & 31;
        bf16x8 v;
        #pragma unroll
        for (int j = 0; j < 8; ++j) v[j] = (short)s[(kb + j) * 32 + c];
        out8[((size_t)cb * 64 + half * 32 + ktl) * 64 + lane] = v;
    }
}

// ---------------------------------------------------------------------------
// cell_mfma: 64 blocks x 256 thr (4 waves). Per step t:
//  PHASE A: t==0 -> tok=START; else redundant token argmax from part (250
//    slots); block 0 merges M/S/L and accumulates CE for step t-1.
//  PHASE B: gates = [emb_tok | h] @ Wcell via MFMA. Wave w: kt = w*16..+15
//    (K 256). A-frag: kt<32 from emb fp32 gather+cvt, else h_bf direct.
//    B-frag: wcell (L2-resident, coalesced). 2x8 MFMA chains.
//  PHASE C: sg LDS combine (4 waves), bias+gate math fp32, cst update,
//    h_bf write (bf16 recurrence).
// C/D layout: col=lane&31, row=(reg&3)+8*(reg>>2)+4*(lane>>5).
// ---------------------------------------------------------------------------
__global__ __launch_bounds__(256) void cell_mfma_kernel(
    const float* __restrict__ emb, const int* __restrict__ labels,
    const void* __restrict__ coin, const int* __restrict__ flag,
    const unsigned short* __restrict__ wcell, const float* __restrict__ bias,
    float* __restrict__ cst, unsigned short* __restrict__ hbf,
    const float* __restrict__ part, float* __restrict__ ce_acc, int t) {
    __shared__ float sg[4][32][32];     // 16 KB [wave][row][lc]
    __shared__ int s_tok[32];
    int tid = threadIdx.x;
    int cb = blockIdx.x;
    int lane = tid & 63, wv = tid >> 6;

    // ---- PHASE A ----
    if (t == 0) {
        if (tid < 32) s_tok[tid] = 1;            // START
    } else {
        int tm1 = t - 1;
        if (tid < 256) {
            int row = tid >> 3, slot = tid & 7;
            float m = -3.0e38f; int mi = 0;
            for (int ib = slot; ib < NLB; ib += 8) {
                int e = row * 256 + ib;
                float pm = part[e];
                int pi = __float_as_int(part[2 * PSTRIDE + e]);
                if (pm > m || (pm == m && pi < mi)) { m = pm; mi = pi; }
            }
            #pragma unroll
            for (int d = 1; d < 8; d <<= 1) {
                float om = __shfl_xor(m, d);
                int omi = __shfl_xor(mi, d);
                if (om > m || (om == m && omi < mi)) { m = om; mi = omi; }
            }
            if (slot == 0) {
                int lab = labels[row * TLEN + tm1];
                int cn = (*flag) ? (int)((const unsigned char*)coin)[row * TLEN + tm1]
                                 : ((const int*)coin)[row * TLEN + tm1];
                s_tok[row] = cn ? mi : lab;
            }
            if (cb == 0) {
                float M = -3.0e38f, S = 0.f, L = -INFINITY;
                for (int ib = slot; ib < NLB; ib += 8) {
                    int e = row * 256 + ib;
                    float pm = part[e], ps = part[PSTRIDE + e];
                    float nM = fmaxf(M, pm);
                    S = S * expf(M - nM) + ps * expf(pm - nM);
                    M = nM;
                    L = fmaxf(L, part[3 * PSTRIDE + e]);
                }
                #pragma unroll
                for (int d = 1; d < 8; d <<= 1) {
                    float oM = __shfl_xor(M, d), oS = __shfl_xor(S, d);
                    float nM = fmaxf(M, oM);
                    S = S * expf(M - nM) + oS * expf(oM - nM);
                    M = nM;
                    L = fmaxf(L, __shfl_xor(L, d));
                }
                if (slot == 0) ce_acc[row] += (M + logf(S)) - L;
            }
        }
    }
    __syncthreads();

    // ---- PHASE B ----
    int r = lane & 31;
    int ksub = (lane >> 5) << 3;       // 0 or 8
    int tok = s_tok[r];
    const bf16x8* wp = (const bf16x8*)wcell + ((size_t)cb * 64 + wv * 16) * 64 + lane;

    f32x16 acc0 = {}, acc1 = {};
    #pragma unroll
    for (int i = 0; i < 8; ++i) {
        int kt = wv * 16 + i;
        int kb = kt * 16 + ksub;
        bf16x8 a;
        if (kt < 32) {
            const float* ep = emb + (size_t)tok * EMBD + kb;
            float4 e0 = *(const float4*)ep;
            float4 e1 = *(const float4*)(ep + 4);
            a[0] = (short)f2bf(e0.x); a[1] = (short)f2bf(e0.y);
            a[2] = (short)f2bf(e0.z); a[3] = (short)f2bf(e0.w);
            a[4] = (short)f2bf(e1.x); a[5] = (short)f2bf(e1.y);
            a[6] = (short)f2bf(e1.z); a[7] = (short)f2bf(e1.w);
        } else {
            a = *(const bf16x8*)&hbf[r * HIDD + (kb - 512)];
        }
        acc0 = __builtin_amdgcn_mfma_f32_32x32x16_bf16(a, wp[i * 64], acc0, 0, 0, 0);
    }
    #pragma unroll
    for (int i = 8; i < 16; ++i) {
        int kt = wv * 16 + i;
        int kb = kt * 16 + ksub;
        bf16x8 a;
        if (kt < 32) {
            const float* ep = emb + (size_t)tok * EMBD + kb;
            float4 e0 = *(const float4*)ep;
            float4 e1 = *(const float4*)(ep + 4);
            a[0] = (short)f2bf(e0.x); a[1] = (short)f2bf(e0.y);
            a[2] = (short)f2bf(e0.z); a[3] = (short)f2bf(e0.w);
            a[4] = (short)f2bf(e1.x); a[5] = (short)f2bf(e1.y);
            a[6] = (short)f2bf(e1.z); a[7] = (short)f2bf(e1.w);
        } else {
            a = *(const bf16x8*)&hbf[r * HIDD + (kb - 512)];
        }
        acc1 = __builtin_amdgcn_mfma_f32_32x32x16_bf16(a, wp[i * 64], acc1, 0, 0, 0);
    }

    int half = lane >> 5;
    #pragma unroll
    for (int reg = 0; reg < 16; ++reg) {
        int row = (reg & 3) + 8 * (reg >> 2) + 4 * half;
        sg[wv][row][lane & 31] = acc0[reg] + acc1[reg];
    }
    __syncthreads();

    // ---- PHASE C ----
    {
        int rr = tid >> 3, jj = tid & 7;
        int jh = cb * 8 + jj;
        float i_ = bias[jh], f_ = bias[jh + 512];
        float g_ = bias[jh + 1024], o_ = bias[jh + 1536];
        #pragma unroll
        for (int w = 0; w < 4; ++w) {
            i_ += sg[w][rr][jj];
            f_ += sg[w][rr][jj + 8];
            g_ += sg[w][rr][jj + 16];
            o_ += sg[w][rr][jj + 24];
        }
        int idx = rr * HIDD + jh;
        float ci = cst[idx];
        float cn = sigmoidf_(f_) * ci + sigmoidf_(i_) * tanhf(g_);
        float hn = sigmoidf_(o_) * tanhf(cn);
        cst[idx] = cn;
        hbf[idx] = f2bf(hn);
    }
}

// ---------------------------------------------------------------------------
// logits_mfma (R8-proven): 250 blocks x 256 thr. Wave = col-group g =
// blk*4+wv, K=512 via 2x16 MFMA chains; h_bf LDS-staged frag-order; per-row
// wave partials + 4-wave LDS combine -> part slot blockIdx (stride 256).
// ---------------------------------------------------------------------------
__global__ __launch_bounds__(256) void logits_mfma_kernel(
    const unsigned short* __restrict__ wot, const unsigned short* __restrict__ h_bf,
    const float* __restrict__ bo, const int* __restrict__ labels,
    float* __restrict__ part, int t) {
    __shared__ __align__(16) unsigned short s_h[16384];   // 32 KB frag-order
    __shared__ int s_lab[32];
    __shared__ float s_pm[4][32], s_ps[4][32], s_pl[4][32], s_pst[4][32];
    __shared__ int s_pi[4][32];
    int tid = threadIdx.x;
    int lane = tid & 63, wv = tid >> 6;

    for (int f = tid; f < 2048; f += 256) {
        int kt = f >> 6, ln = f & 63;
        int row = ln & 31, kb = kt * 16 + ((ln >> 5) << 3);
        *(bf16x8*)&s_h[f * 8] = *(const bf16x8*)&h_bf[row * 512 + kb];
    }
    if (tid < 32) s_lab[tid] = labels[tid * TLEN + t];
    __syncthreads();

    int g = blockIdx.x * 4 + wv;                 // col-group 0..999
    const bf16x8* wp = (const bf16x8*)wot + (size_t)g * 2048 + lane;
    const bf16x8* sh8 = (const bf16x8*)s_h;

    f32x16 acc0 = {}, acc1 = {};
    #pragma unroll 4
    for (int kt = 0; kt < 16; ++kt) {
        acc0 = __builtin_amdgcn_mfma_f32_32x32x16_bf16(
            sh8[kt * 64 + lane], wp[kt * 64], acc0, 0, 0, 0);
        acc1 = __builtin_amdgcn_mfma_f32_32x32x16_bf16(
            sh8[(kt + 16) * 64 + lane], wp[(kt + 16) * 64], acc1, 0, 0, 0);
    }

    int half = lane >> 5;
    int colw = lane & 31;
    int col = g * 32 + colw;
    float bq = bo[col];

    #pragma unroll
    for (int reg = 0; reg < 16; ++reg) {
        int row = (reg & 3) + 8 * (reg >> 2) + 4 * half;
        float v = acc0[reg] + acc1[reg] + bq;
        float m = v; int mi = col;
        #pragma unroll
        for (int d = 1; d < 32; d <<= 1) {
            float om = __shfl_xor(m, d);
            int omi = __shfl_xor(mi, d);
            if (om > m || (om == m && omi < mi)) { m = om; mi = omi; }
        }
        float e = expf(v - m), ssum = e;
        #pragma unroll
        for (int d = 1; d < 32; d <<= 1) ssum += __shfl_xor(ssum, d);
        int labc = s_lab[row];
        float lv = __shfl(v, (labc & 31) + (half << 5));
        if ((labc >> 5) != g) lv = -INFINITY;
        float sv = __shfl(v, 2 + (half << 5));   // STOP = 2
        if (g != 0) sv = -INFINITY;
        if (colw == 0) {
            s_pm[wv][row] = m; s_ps[wv][row] = ssum; s_pi[wv][row] = mi;
            s_pl[wv][row] = lv; s_pst[wv][row] = sv;
        }
    }
    __syncthreads();

    if (tid < 32) {
        int row = tid;
        float M = s_pm[0][row], S = s_ps[0][row];
        int MI = s_pi[0][row];
        float L = s_pl[0][row], ST = s_pst[0][row];
        #pragma unroll
        for (int w = 1; w < 4; ++w) {
            float pm = s_pm[w][row], ps = s_ps[w][row];
            int pi = s_pi[w][row];
            float nM = fmaxf(M, pm);
            S = S * expf(M - nM) + ps * expf(pm - nM);
            if (pm > M || (pm == M && pi < MI)) MI = pi;
            M = nM;
            L = fmaxf(L, s_pl[w][row]);
            ST = fmaxf(ST, s_pst[w][row]);
        }
        int e0 = row * 256 + blockIdx.x;
        part[e0] = M;
        part[PSTRIDE + e0] = S;
        part[2 * PSTRIDE + e0] = __int_as_float(MI);
        part[3 * PSTRIDE + e0] = L;
        part[4 * PSTRIDE + e0] = ST;
    }
}

// ---------------------------------------------------------------------------
// finalize3: STOP-step CE from part(t=32); out = (ce_acc + final)/32
// ---------------------------------------------------------------------------
__global__ __launch_bounds__(256) void finalize3_kernel(
    const float* __restrict__ part, const float* __restrict__ ce_acc,
    float* __restrict__ out) {
    __shared__ float s_ce[32];
    int tid = threadIdx.x;
    int row = tid >> 3, slot = tid & 7;
    float M = -3.0e38f, S = 0.f, ST = -INFINITY;
    for (int ib = slot; ib < NLB; ib += 8) {
        int e = row * 256 + ib;
        float pm = part[e], ps = part[PSTRIDE + e];
        float nM = fmaxf(M, pm);
        S = S * expf(M - nM) + ps * expf(pm - nM);
        M = nM;
        ST = fmaxf(ST, part[4 * PSTRIDE + e]);
    }
    #pragma unroll
    for (int d = 1; d < 8; d <<= 1) {
        float oM = __shfl_xor(M, d), oS = __shfl_xor(S, d);
        float nM = fmaxf(M, oM);
        S = S * expf(M - nM) + oS * expf(oM - nM);
        M = nM;
        ST = fmaxf(ST, __shfl_xor(ST, d));
    }
    if (slot == 0) s_ce[row] = ce_acc[row] + (M + logf(S)) - ST;
    __syncthreads();
    if (tid == 0) {
        float tot = 0.f;
        for (int r = 0; r < 32; ++r) tot += s_ce[r];
        *out = tot / 32.f;
    }
}

// ---------------------------------------------------------------------------
// FALLBACK cell (fp32, R10-proven structure; 250-slot parts): used only if
// ws too small for wcell. Slow but correct.
// ---------------------------------------------------------------------------
__global__ __launch_bounds__(512) void cell_fb_kernel(
    const float* __restrict__ emb, const int* __restrict__ labels,
    const void* __restrict__ coin, const int* __restrict__ flag,
    const float* __restrict__ Wi, const float* __restrict__ Wh,
    const float* __restrict__ hsrc, const float* __restrict__ bias,
    float* __restrict__ cst, float* __restrict__ hdst,
    unsigned short* __restrict__ hbf, const float* __restrict__ part,
    float* __restrict__ ce_acc, int t) {
    __shared__ float s_x[32][261];
    __shared__ float sg[8][32][32];
    __shared__ int s_tok[32];
    int tid = threadIdx.x;
    int cb = blockIdx.x;

    if (t == 0) {
        if (tid < 32) s_tok[tid] = 1;
    } else if (tid < 256) {
        int row = tid >> 3, slot = tid & 7;
        int tm1 = t - 1;
        float m = -3.0e38f; int mi = 0;
        for (int ib = slot; ib < NLB; ib += 8) {
            int e = row * 256 + ib;
            float pm = part[e];
            int pi = __float_as_int(part[2 * PSTRIDE + e]);
            if (pm > m || (pm == m && pi < mi)) { m = pm; mi = pi; }
        }
        #pragma unroll
        for (int d = 1; d < 8; d <<= 1) {
            float om = __shfl_xor(m, d);
            int omi = __shfl_xor(mi, d);
            if (om > m || (om == m && omi < mi)) { m = om; mi = omi; }
        }
        if (slot == 0) {
            int lab = labels[row * TLEN + tm1];
            int cn = (*flag) ? (int)((const unsigned char*)coin)[row * TLEN + tm1]
                             : ((const int*)coin)[row * TLEN + tm1];
            s_tok[row] = cn ? mi : lab;
        }
        if (cb == 0) {
            float M = -3.0e38f, S = 0.f, L = -INFINITY;
            for (int ib = slot; ib < NLB; ib += 8) {
                int e = row * 256 + ib;
                float pm = part[e], ps = part[PSTRIDE + e];
                float nM = fmaxf(M, pm);
                S = S * expf(M - nM) + ps * expf(pm - nM);
                M = nM;
                L = fmaxf(L, part[3 * PSTRIDE + e]);
            }
            #pragma unroll
            for (int d = 1; d < 8; d <<= 1) {
                float oM = __shfl_xor(M, d), oS = __shfl_xor(S, d);
                float nM = fmaxf(M, oM);
                S = S * expf(M - nM) + oS * expf(oM - nM);
                M = nM;
                L = fmaxf(L, __shfl_xor(L, d));
            }
            if (slot == 0) ce_acc[row] += (M + logf(S)) - L;
        }
    }
    __syncthreads();

    int colq = tid & 7;
    int rowg = (tid >> 3) & 7;
    int ksl = tid >> 6;
    int g = colq >> 1, q = colq & 1;
    int col = g * 512 + cb * 8 + q * 4;
    float acc[4][4] = {{0.f,0.f,0.f,0.f},{0.f,0.f,0.f,0.f},
                       {0.f,0.f,0.f,0.f},{0.f,0.f,0.f,0.f}};
    for (int ch = 0; ch < 4; ++ch) {
        int kb = ch * 256;
        int ko = (kb < 512) ? kb : (kb - 512);
        #pragma unroll
        for (int it = 0; it < 4; ++it) {
            int i4 = it * 512 + tid;
            int r = i4 >> 6;
            int kk = (i4 & 63) << 2;
            float4 v;
            if (kb < 512)
                v = *(const float4*)&emb[(size_t)s_tok[r] * EMBD + ko + kk];
            else
                v = *(const float4*)&hsrc[r * HIDD + ko + kk];
            s_x[r][kk] = v.x; s_x[r][kk + 1] = v.y;
            s_x[r][kk + 2] = v.z; s_x[r][kk + 3] = v.w;
        }
        __syncthreads();
        const float* W = (kb < 512) ? (Wi + (size_t)kb * G4)
                                    : (Wh + (size_t)(kb - 512) * G4);
        int k0 = ksl * 32;
        #pragma unroll 4
        for (int kk = k0; kk < k0 + 32; ++kk) {
            float4 w = *(const float4*)&W[(size_t)kk * G4 + col];
            float x0 = s_x[rowg * 4 + 0][kk];
            float x1 = s_x[rowg * 4 + 1][kk];
            float x2 = s_x[rowg * 4 + 2][kk];
            float x3 = s_x[rowg * 4 + 3][kk];
            acc[0][0] += x0 * w.x; acc[0][1] += x0 * w.y;
            acc[0][2] += x0 * w.z; acc[0][3] += x0 * w.w;
            acc[1][0] += x1 * w.x; acc[1][1] += x1 * w.y;
            acc[1][2] += x1 * w.z; acc[1][3] += x1 * w.w;
            acc[2][0] += x2 * w.x; acc[2][1] += x2 * w.y;
            acc[2][2] += x2 * w.z; acc[2][3] += x2 * w.w;
            acc[3][0] += x3 * w.x; acc[3][1] += x3 * w.y;
            acc[3][2] += x3 * w.z; acc[3][3] += x3 * w.w;
        }
        __syncthreads();
    }
    #pragma unroll
    for (int rr = 0; rr < 4; ++rr)
        #pragma unroll
        for (int cc = 0; cc < 4; ++cc)
            sg[ksl][rowg * 4 + rr][g * 8 + q * 4 + cc] = acc[rr][cc];
    __syncthreads();
    if (tid < 256) {
        int r = tid >> 3, jj = tid & 7;
        int jh = cb * 8 + jj;
        float i_ = bias[jh], f_ = bias[jh + 512];
        float g_ = bias[jh + 1024], o_ = bias[jh + 1536];
        #pragma unroll
        for (int s2 = 0; s2 < 8; ++s2) {
            i_ += sg[s2][r][jj];
            f_ += sg[s2][r][jj + 8];
            g_ += sg[s2][r][jj + 16];
            o_ += sg[s2][r][jj + 24];
        }
        int idx = r * HIDD + jh;
        float ci = cst[idx];
        float cn = sigmoidf_(f_) * ci + sigmoidf_(i_) * tanhf(g_);
        float hn = sigmoidf_(o_) * tanhf(cn);
        cst[idx] = cn;
        hdst[idx] = hn;
        hbf[idx] = f2bf(hn);
    }
}

// ===========================================================================
extern "C" void kernel_launch(void* const* d_in, const int* in_sizes, int n_in,
                              void* d_out, int out_size, void* d_ws, size_t ws_size,
                              hipStream_t stream) {
    const float* x      = (const float*)d_in[0];
    const int*   labels = (const int*)  d_in[1];
    const void*  coin   =               d_in[2];
    const float* emb    = (const float*)d_in[3];
    const float* Wi     = (const float*)d_in[4];
    const float* Wh     = (const float*)d_in[5];
    const float* b      = (const float*)d_in[6];
    const float* Wo     = (const float*)d_in[7];
    const float* bo     = (const float*)d_in[8];

    float* ws     = (float*)d_ws;
    float* hA     = ws;                        // 16384 (fallback)
    float* hB     = ws + 16384;                // 16384 (fallback)
    float* cst    = ws + 32768;                // 16384
    unsigned short* h_bf = (unsigned short*)(ws + 49152);   // 8192 floats
    float* part   = ws + 57344;                // 5*8192 = 40960
    float* ce_acc = ws + 98304;                // 32
    int*   flag   = (int*)(ws + 98336);        // 1 (+pad)
    unsigned short* wot   = (unsigned short*)(ws + 98368);  // 8192000 floats
    unsigned short* wcell = (unsigned short*)(ws + 98368 + 8192000); // 1048576 floats
    float* outp   = (float*)d_out;

    size_t need_full = (size_t)(98368 + 8192000 + 1048576) * 4;

    wot_prep_kernel<<<NGRP, 256, 0, stream>>>(Wo, wot);
    init3_kernel<<<1, 256, 0, stream>>>(x, coin, hA, cst, h_bf, ce_acc, flag);

    if (ws_size >= need_full) {
        wcell_prep_kernel<<<128, 256, 0, stream>>>(Wi, Wh, wcell);
        for (int t = 0; t < 33; ++t) {
            int tt = (t < 32) ? t : 0;
            cell_mfma_kernel<<<64, 256, 0, stream>>>(emb, labels, coin, flag,
                                                     wcell, b, cst, h_bf,
                                                     part, ce_acc, t);
            logits_mfma_kernel<<<NLB, 256, 0, stream>>>(wot, h_bf, bo, labels,
                                                        part, tt);
        }
    } else {
        float* hsrc = hA;
        float* hdst = hB;
        for (int t = 0; t < 33; ++t) {
            int tt = (t < 32) ? t : 0;
            cell_fb_kernel<<<64, 512, 0, stream>>>(emb, labels, coin, flag,
                                                   Wi, Wh, hsrc, b, cst, hdst,
                                                   h_bf, part, ce_acc, t);
            logits_mfma_kernel<<<NLB, 256, 0, stream>>>(wot, h_bf, bo, labels,
                                                        part, tt);
            float* tmp = hsrc; hsrc = hdst; hdst = tmp;
        }
    }
    finalize3_kernel<<<1, 256, 0, stream>>>(part, ce_acc, outp);
}

// Round 12
// 1385.632 us; speedup vs baseline: 2.3470x; 1.1040x over previous
//
#include <hip/hip_runtime.h>
#include <math.h>

#define VOCABSZ 32000
#define EMBD 512
#define HIDD 512
#define BSZ 32
#define TLEN 32
#define G4 2048
#define NGRP 1000            // wot col-groups of 32
#define NSLOT 500            // logits partial slots (1 per block)
#define SSTRIDE 512          // slot stride per row
#define PSTRIDE 16384        // part SoA array stride (32 rows * 512)

using bf16x8 = __attribute__((ext_vector_type(8))) short;
using f32x16 = __attribute__((ext_vector_type(16))) float;

__device__ __forceinline__ float sigmoidf_(float x) { return 1.f / (1.f + expf(-x)); }
__device__ __forceinline__ unsigned short f2bf(float f) {
    unsigned u = __float_as_uint(f);
    return (unsigned short)((u + 0x7fffu + ((u >> 16) & 1u)) >> 16);   // RNE
}

// ---------------------------------------------------------------------------
// init4: cst <- 0, h_bf <- bf16(x), ce_acc <- 0, coin dtype probe
// ---------------------------------------------------------------------------
__global__ void init4_kernel(const float* __restrict__ x,
                             const void* __restrict__ coin,
                             float* __restrict__ cst,
                             unsigned short* __restrict__ hbf,
                             float* __restrict__ ce_acc, int* __restrict__ flag) {
    int tid = threadIdx.x;
    if (tid == 0) {
        // coin dtype probe: uint8 bools pack to words like 0x00010001 (>1)
        const unsigned int* cw = (const unsigned int*)coin;
        int f = 0;
        for (int i = 0; i < 256; ++i) if (cw[i] > 1u) f = 1;
        *flag = f;
    }
    if (tid < 32) ce_acc[tid] = 0.f;
    for (int i = tid; i < BSZ * HIDD; i += blockDim.x) {
        cst[i] = 0.f;
        hbf[i] = f2bf(x[i]);
    }
}

// ---------------------------------------------------------------------------
// wot_prep (R8-proven): Wo [512][32000] fp32 -> bf16 MFMA B-frag order:
//   wot8[(g*32 + kt)*64 + lane] = Wo[kt*16+(lane>>5)*8+j][g*32+(lane&31)]
// ---------------------------------------------------------------------------
__global__ __launch_bounds__(256) void wot_prep_kernel(
    const float* __restrict__ Wo, unsigned short* __restrict__ wot) {
    __shared__ unsigned short s[512 * 32];     // [k][col] 32 KB
    int g = blockIdx.x;
    int tid = threadIdx.x;
    int col = tid & 31;
    int k0 = tid >> 5;
    for (int kk = k0; kk < 512; kk += 8)
        s[kk * 32 + col] = f2bf(Wo[(size_t)kk * VOCABSZ + g * 32 + col]);
    __syncthreads();
    bf16x8* out8 = (bf16x8*)wot;
    for (int f = tid; f < 2048; f += 256) {
        int kt = f >> 6, lane = f & 63;
        int kb = kt * 16 + ((lane >> 5) << 3);
        int c = lane & 31;
        bf16x8 v;
        #pragma unroll
        for (int j = 0; j < 8; ++j) v[j] = (short)s[(kb + j) * 32 + c];
        out8[(size_t)g * 2048 + f] = v;
    }
}

// ---------------------------------------------------------------------------
// wcell_prep (R11-verified): Wi/Wh -> bf16 B-frag order block-packed:
//   wcell8[(cb*64 + half*32 + ktl)*64 + lane], block cb owns
//   gcol = (lc>>3)*512 + cb*8 + (lc&7), lc = lane&31.
// ---------------------------------------------------------------------------
__global__ __launch_bounds__(256) void wcell_prep_kernel(
    const float* __restrict__ Wi, const float* __restrict__ Wh,
    unsigned short* __restrict__ wcell) {
    __shared__ unsigned short s[512 * 32];     // [kl][lc] 32 KB
    int cb = blockIdx.x >> 1;
    int half = blockIdx.x & 1;
    const float* Wsrc = half ? Wh : Wi;
    int tid = threadIdx.x;
    int lc = tid & 31;
    int gcol = (lc >> 3) * 512 + cb * 8 + (lc & 7);
    int k0 = tid >> 5;
    for (int kl = k0; kl < 512; kl += 8)
        s[kl * 32 + lc] = f2bf(Wsrc[(size_t)kl * G4 + gcol]);
    __syncthreads();
    bf16x8* out8 = (bf16x8*)wcell;
    for (int f = tid; f < 2048; f += 256) {
        int ktl = f >> 6, lane = f & 63;
        int kb = ktl * 16 + ((lane >> 5) << 3);
        int c = lane & 31;
        bf16x8 v;
        #pragma unroll
        for (int j = 0; j < 8; ++j) v[j] = (short)s[(kb + j) * 32 + c];
        out8[((size_t)cb * 64 + half * 32 + ktl) * 64 + lane] = v;
    }
}

// ---------------------------------------------------------------------------
// cell_mfma2: 64 blocks x 1024 thr (16 waves = 4/SIMD). Per step t:
//  PHASE A: t==0 -> tok=START; else token argmax from part (500 slots,
//    32 slots/row, 16 iters); block 0 merges M/S/L, accumulates CE(t-1).
//  PHASE B: wave wv owns kt = wv*4..+3 (one 4-MFMA chain). wv<8: A-frag
//    from emb[tok[lane&31]] fp32+cvt; wv>=8: from h_bf direct. B-frag wcell
//    (L2-resident, coalesced). sg[16][32][32] LDS combine (conflict-free).
//  PHASE C: st[32][33] totals; 256 thr gate math fp32; cst, h_bf update.
// C/D layout: col=lane&31, row=(reg&3)+8*(reg>>2)+4*(lane>>5).
// ---------------------------------------------------------------------------
__global__ __launch_bounds__(1024) void cell_mfma2_kernel(
    const float* __restrict__ emb, const int* __restrict__ labels,
    const void* __restrict__ coin, const int* __restrict__ flag,
    const unsigned short* __restrict__ wcell, const float* __restrict__ bias,
    float* __restrict__ cst, unsigned short* __restrict__ hbf,
    const float* __restrict__ part, float* __restrict__ ce_acc, int t) {
    __shared__ float sg[16][32][32];    // 64 KB [wave][row][lc]
    __shared__ float st[32][33];        // 4.2 KB combined gates
    __shared__ int s_tok[32];
    int tid = threadIdx.x;
    int cb = blockIdx.x;
    int lane = tid & 63, wv = tid >> 6;

    // ---- PHASE A ----
    if (t == 0) {
        if (tid < 32) s_tok[tid] = 1;            // START
    } else {
        int row = tid >> 5, slot = tid & 31;
        int tm1 = t - 1;
        float m = -3.0e38f; int mi = 0;
        for (int ib = slot; ib < NSLOT; ib += 32) {
            int e = row * SSTRIDE + ib;
            float pm = part[e];
            int pi = __float_as_int(part[2 * PSTRIDE + e]);
            if (pm > m || (pm == m && pi < mi)) { m = pm; mi = pi; }
        }
        #pragma unroll
        for (int d = 1; d < 32; d <<= 1) {
            float om = __shfl_xor(m, d);
            int omi = __shfl_xor(mi, d);
            if (om > m || (om == m && omi < mi)) { m = om; mi = omi; }
        }
        if (slot == 0) {
            int lab = labels[row * TLEN + tm1];
            int cn = (*flag) ? (int)((const unsigned char*)coin)[row * TLEN + tm1]
                             : ((const int*)coin)[row * TLEN + tm1];
            s_tok[row] = cn ? mi : lab;
        }
        if (cb == 0) {
            float M = -3.0e38f, S = 0.f, L = -INFINITY;
            for (int ib = slot; ib < NSLOT; ib += 32) {
                int e = row * SSTRIDE + ib;
                float pm = part[e], ps = part[PSTRIDE + e];
                float nM = fmaxf(M, pm);
                S = S * expf(M - nM) + ps * expf(pm - nM);
                M = nM;
                L = fmaxf(L, part[3 * PSTRIDE + e]);
            }
            #pragma unroll
            for (int d = 1; d < 32; d <<= 1) {
                float oM = __shfl_xor(M, d), oS = __shfl_xor(S, d);
                float nM = fmaxf(M, oM);
                S = S * expf(M - nM) + oS * expf(oM - nM);
                M = nM;
                L = fmaxf(L, __shfl_xor(L, d));
            }
            if (slot == 0) ce_acc[row] += (M + logf(S)) - L;
        }
    }
    __syncthreads();

    // ---- PHASE B ----
    int r = lane & 31;
    int ksub = (lane >> 5) << 3;       // 0 or 8
    const bf16x8* wp = (const bf16x8*)wcell + ((size_t)cb * 64 + wv * 4) * 64 + lane;

    f32x16 acc = {};
    if (wv < 8) {
        const float* ebase = emb + (size_t)s_tok[r] * EMBD;
        #pragma unroll
        for (int i = 0; i < 4; ++i) {
            int k = (wv * 4 + i) * 16 + ksub;
            float4 e0 = *(const float4*)(ebase + k);
            float4 e1 = *(const float4*)(ebase + k + 4);
            bf16x8 a;
            a[0] = (short)f2bf(e0.x); a[1] = (short)f2bf(e0.y);
            a[2] = (short)f2bf(e0.z); a[3] = (short)f2bf(e0.w);
            a[4] = (short)f2bf(e1.x); a[5] = (short)f2bf(e1.y);
            a[6] = (short)f2bf(e1.z); a[7] = (short)f2bf(e1.w);
            acc = __builtin_amdgcn_mfma_f32_32x32x16_bf16(a, wp[i * 64], acc, 0, 0, 0);
        }
    } else {
        #pragma unroll
        for (int i = 0; i < 4; ++i) {
            int k = (wv * 4 + i) * 16 + ksub - 512;
            bf16x8 a = *(const bf16x8*)&hbf[r * HIDD + k];
            acc = __builtin_amdgcn_mfma_f32_32x32x16_bf16(a, wp[i * 64], acc, 0, 0, 0);
        }
    }

    int half = lane >> 5;
    #pragma unroll
    for (int reg = 0; reg < 16; ++reg) {
        int row = (reg & 3) + 8 * (reg >> 2) + 4 * half;
        sg[wv][row][lane & 31] = acc[reg];
    }
    __syncthreads();

    // combine 16 waves
    {
        int row = tid >> 5, lc = tid & 31;
        float s = 0.f;
        #pragma unroll
        for (int w = 0; w < 16; ++w) s += sg[w][row][lc];
        st[row][lc] = s;
    }
    __syncthreads();

    // ---- PHASE C ----
    if (tid < 256) {
        int rr = tid >> 3, jj = tid & 7;
        int jh = cb * 8 + jj;
        float i_ = bias[jh]        + st[rr][jj];
        float f_ = bias[jh + 512]  + st[rr][jj + 8];
        float g_ = bias[jh + 1024] + st[rr][jj + 16];
        float o_ = bias[jh + 1536] + st[rr][jj + 24];
        int idx = rr * HIDD + jh;
        float ci = cst[idx];
        float cn = sigmoidf_(f_) * ci + sigmoidf_(i_) * tanhf(g_);
        float hn = sigmoidf_(o_) * tanhf(cn);
        cst[idx] = cn;
        hbf[idx] = f2bf(hn);
    }
}

// ---------------------------------------------------------------------------
// logits_split: 500 blocks x 256 thr (2 blocks/CU, 2 waves/SIMD). Block owns
// 2 col-groups (g0=blk*2, g1=blk*2+1) x split-K 2. Wave wv: group p=wv&1,
// K-half kh=wv>>1 -> 16 MFMAs (2x8 chains). Pair-combine via padded LDS
// sacc[4][64][17]; waves 0,1 run R8-proven epilogue per group; tid<32 merges
// the 2 ordered groups -> part slot blockIdx (stride 512).
// ---------------------------------------------------------------------------
__global__ __launch_bounds__(256, 2) void logits_split_kernel(
    const unsigned short* __restrict__ wot, const unsigned short* __restrict__ h_bf,
    const float* __restrict__ bo, const int* __restrict__ labels,
    float* __restrict__ part, int t) {
    __shared__ __align__(16) unsigned short s_h[16384];   // 32 KB frag-order
    __shared__ float sacc[4][64][17];                     // 17.4 KB
    __shared__ int s_lab[32];
    __shared__ float s_pm[2][32], s_ps[2][32], s_pl[2][32], s_pst[2][32];
    __shared__ int s_pi[2][32];
    int tid = threadIdx.x;
    int lane = tid & 63, wv = tid >> 6;
    int ls = (t < 32) ? t : 0;

    for (int f = tid; f < 2048; f += 256) {
        int kt = f >> 6, ln = f & 63;
        int row = ln & 31, kb = kt * 16 + ((ln >> 5) << 3);
        *(bf16x8*)&s_h[f * 8] = *(const bf16x8*)&h_bf[row * 512 + kb];
    }
    if (tid < 32) s_lab[tid] = labels[tid * TLEN + ls];
    __syncthreads();

    int p = wv & 1, kh = wv >> 1;
    int g = blockIdx.x * 2 + p;
    const bf16x8* wp = (const bf16x8*)wot + (size_t)g * 2048 + lane;
    const bf16x8* sh8 = (const bf16x8*)s_h;

    f32x16 a0 = {}, a1 = {};
    #pragma unroll
    for (int i = 0; i < 8; ++i) {
        int kt = kh * 16 + i;
        a0 = __builtin_amdgcn_mfma_f32_32x32x16_bf16(
            sh8[kt * 64 + lane], wp[kt * 64], a0, 0, 0, 0);
        a1 = __builtin_amdgcn_mfma_f32_32x32x16_bf16(
            sh8[(kt + 8) * 64 + lane], wp[(kt + 8) * 64], a1, 0, 0, 0);
    }
    #pragma unroll
    for (int reg = 0; reg < 16; ++reg)
        sacc[wv][lane][reg] = a0[reg] + a1[reg];
    __syncthreads();

    if (wv < 2) {
        int half = lane >> 5;
        int colw = lane & 31;
        int gcol = blockIdx.x * 2 + wv;          // this wave's group
        int col = gcol * 32 + colw;
        float bq = bo[col];
        #pragma unroll
        for (int reg = 0; reg < 16; ++reg) {
            int row = (reg & 3) + 8 * (reg >> 2) + 4 * half;
            float v = sacc[wv][lane][reg] + sacc[wv + 2][lane][reg] + bq;
            float m = v; int mi = col;
            #pragma unroll
            for (int d = 1; d < 32; d <<= 1) {
                float om = __shfl_xor(m, d);
                int omi = __shfl_xor(mi, d);
                if (om > m || (om == m && omi < mi)) { m = om; mi = omi; }
            }
            float e = expf(v - m), ssum = e;
            #pragma unroll
            for (int d = 1; d < 32; d <<= 1) ssum += __shfl_xor(ssum, d);
            int labc = s_lab[row];
            float lv = __shfl(v, (labc & 31) + (half << 5));
            if ((labc >> 5) != gcol) lv = -INFINITY;
            float sv = __shfl(v, 2 + (half << 5));   // STOP = 2
            if (gcol != 0) sv = -INFINITY;
            if (colw == 0) {
                s_pm[wv][row] = m; s_ps[wv][row] = ssum; s_pi[wv][row] = mi;
                s_pl[wv][row] = lv; s_pst[wv][row] = sv;
            }
        }
    }
    __syncthreads();

    if (tid < 32) {
        int row = tid;
        float M = s_pm[0][row], S = s_ps[0][row];
        int MI = s_pi[0][row];
        float L = s_pl[0][row], ST = s_pst[0][row];
        {
            float pm = s_pm[1][row], ps = s_ps[1][row];
            int pi = s_pi[1][row];
            float nM = fmaxf(M, pm);
            S = S * expf(M - nM) + ps * expf(pm - nM);
            if (pm > M || (pm == M && pi < MI)) MI = pi;
            M = nM;
            L = fmaxf(L, s_pl[1][row]);
            ST = fmaxf(ST, s_pst[1][row]);
        }
        int e0 = row * SSTRIDE + blockIdx.x;
        part[e0] = M;
        part[PSTRIDE + e0] = S;
        part[2 * PSTRIDE + e0] = __int_as_float(MI);
        part[3 * PSTRIDE + e0] = L;
        part[4 * PSTRIDE + e0] = ST;
    }
}

// ---------------------------------------------------------------------------
// finalize4: STOP-step CE from part(t=32); out = (ce_acc + final)/32
// ---------------------------------------------------------------------------
__global__ __launch_bounds__(256) void finalize4_kernel(
    const float* __restrict__ part, const float* __restrict__ ce_acc,
    float* __restrict__ out) {
    __shared__ float s_ce[32];
    int tid = threadIdx.x;
    int row = tid >> 3, slot = tid & 7;
    float M = -3.0e38f, S = 0.f, ST = -INFINITY;
    for (int ib = slot; ib < NSLOT; ib += 8) {
        int e = row * SSTRIDE + ib;
        float pm = part[e], ps = part[PSTRIDE + e];
        float nM = fmaxf(M, pm);
        S = S * expf(M - nM) + ps * expf(pm - nM);
        M = nM;
        ST = fmaxf(ST, part[4 * PSTRIDE + e]);
    }
    #pragma unroll
    for (int d = 1; d < 8; d <<= 1) {
        float oM = __shfl_xor(M, d), oS = __shfl_xor(S, d);
        float nM = fmaxf(M, oM);
        S = S * expf(M - nM) + oS * expf(oM - nM);
        M = nM;
        ST = fmaxf(ST, __shfl_xor(ST, d));
    }
    if (slot == 0) s_ce[row] = ce_acc[row] + (M + logf(S)) - ST;
    __syncthreads();
    if (tid == 0) {
        float tot = 0.f;
        for (int r = 0; r < 32; ++r) tot += s_ce[r];
        *out = tot / 32.f;
    }
}

// ===========================================================================
extern "C" void kernel_launch(void* const* d_in, const int* in_sizes, int n_in,
                              void* d_out, int out_size, void* d_ws, size_t ws_size,
                              hipStream_t stream) {
    const float* x      = (const float*)d_in[0];
    const int*   labels = (const int*)  d_in[1];
    const void*  coin   =               d_in[2];
    const float* emb    = (const float*)d_in[3];
    const float* Wi     = (const float*)d_in[4];
    const float* Wh     = (const float*)d_in[5];
    const float* b      = (const float*)d_in[6];
    const float* Wo     = (const float*)d_in[7];
    const float* bo     = (const float*)d_in[8];

    float* ws     = (float*)d_ws;
    float* cst    = ws;                        // 16384
    unsigned short* h_bf = (unsigned short*)(ws + 16384);   // 8192 floats
    float* part   = ws + 24576;                // 5*16384 = 81920
    float* ce_acc = ws + 106496;               // 32
    int*   flag   = (int*)(ws + 106528);       // 1 (+pad)
    unsigned short* wcell = (unsigned short*)(ws + 106560); // 1048576 floats
    unsigned short* wot   = (unsigned short*)(ws + 1155136); // 8192000 floats
    float* outp   = (float*)d_out;

    wot_prep_kernel<<<NGRP, 256, 0, stream>>>(Wo, wot);
    wcell_prep_kernel<<<128, 256, 0, stream>>>(Wi, Wh, wcell);
    init4_kernel<<<1, 256, 0, stream>>>(x, coin, cst, h_bf, ce_acc, flag);

    for (int t = 0; t < 33; ++t) {
        cell_mfma2_kernel<<<64, 1024, 0, stream>>>(emb, labels, coin, flag,
                                                   wcell, b, cst, h_bf,
                                                   part, ce_acc, t);
        logits_split_kernel<<<NSLOT, 256, 0, stream>>>(wot, h_bf, bo, labels,
                                                       part, t);
    }
    finalize4_kernel<<<1, 256, 0, stream>>>(part, ce_acc, outp);
}

// Round 13
// 1250.692 us; speedup vs baseline: 2.6002x; 1.1079x over previous
//
#include <hip/hip_runtime.h>
#include <math.h>

#define VOCABSZ 32000
#define EMBD 512
#define HIDD 512
#define BSZ 32
#define TLEN 32
#define G4 2048
#define NGRP 1000            // wot col-groups of 32
#define NLB 250              // logits blocks / partial slots
#define PSTRIDE 8192         // part SoA stride (32 rows * 256 slots)
#define SW 256.0f            // Wo fp8 scale
#define SH 16.0f             // h fp8 scale
#define INV_SWH (1.0f / (SW * SH))

using bf16x8 = __attribute__((ext_vector_type(8))) short;
using f32x16 = __attribute__((ext_vector_type(16))) float;
typedef long long i64;

__device__ __forceinline__ float sigmoidf_(float x) { return 1.f / (1.f + expf(-x)); }
__device__ __forceinline__ unsigned short f2bf(float f) {
    unsigned u = __float_as_uint(f);
    return (unsigned short)((u + 0x7fffu + ((u >> 16) & 1u)) >> 16);   // RNE
}
// float -> OCP e4m3fn, RNE, FTZ for |x| < 2^-6 (negligible for our data)
__device__ __forceinline__ unsigned char f2e4m3(float f) {
    unsigned u = __float_as_uint(f);
    unsigned s = (u >> 24) & 0x80u;
    int e = (int)((u >> 23) & 0xffu);
    unsigned m = u & 0x7fffffu;
    int ee = e - 120;                    // e4m3 biased exponent
    if (ee >= 16) return (unsigned char)(s | 0x7E);   // saturate to 448
    if (ee <= 0) return (unsigned char)s;             // FTZ
    unsigned r = m + 0x7FFFFu + ((m >> 20) & 1u);     // RNE to 3 mant bits
    if (r & 0x800000u) { ee += 1; r = 0; if (ee >= 16) return (unsigned char)(s | 0x7E); }
    unsigned mant = (r >> 20) & 7u;
    if (ee == 15 && mant == 7u) return (unsigned char)(s | 0x7E);  // avoid NaN enc
    return (unsigned char)(s | (unsigned)(ee << 3) | mant);
}

// ---------------------------------------------------------------------------
// init5: cst <- 0, h_bf <- bf16(x), h_f8 <- e4m3(x*SH), ce_acc <- 0, probe
// ---------------------------------------------------------------------------
__global__ void init5_kernel(const float* __restrict__ x,
                             const void* __restrict__ coin,
                             float* __restrict__ cst,
                             unsigned short* __restrict__ hbf,
                             unsigned char* __restrict__ hf8,
                             float* __restrict__ ce_acc, int* __restrict__ flag) {
    int tid = threadIdx.x;
    if (tid == 0) {
        // coin dtype probe: uint8 bools pack to words like 0x00010001 (>1)
        const unsigned int* cw = (const unsigned int*)coin;
        int f = 0;
        for (int i = 0; i < 256; ++i) if (cw[i] > 1u) f = 1;
        *flag = f;
    }
    if (tid < 32) ce_acc[tid] = 0.f;
    for (int i = tid; i < BSZ * HIDD; i += blockDim.x) {
        float v = x[i];
        cst[i] = 0.f;
        hbf[i] = f2bf(v);
        hf8[i] = f2e4m3(v * SH);
    }
}

// ---------------------------------------------------------------------------
// wot8_prep: Wo [512][32000] fp32 -> e4m3(Wo*SW) in MFMA B-frag order:
//   byte j of wot8[g*2048 + kt*64 + lane] = Wo[kt*16+(lane>>5)*8+j][g*32+(lane&31)]
// ---------------------------------------------------------------------------
__global__ __launch_bounds__(256) void wot8_prep_kernel(
    const float* __restrict__ Wo, i64* __restrict__ wot8) {
    __shared__ unsigned char s[512 * 32];      // [k][col] 16 KB
    int g = blockIdx.x;
    int tid = threadIdx.x;
    int col = tid & 31;
    int k0 = tid >> 5;
    for (int kk = k0; kk < 512; kk += 8)
        s[kk * 32 + col] = f2e4m3(Wo[(size_t)kk * VOCABSZ + g * 32 + col] * SW);
    __syncthreads();
    for (int f = tid; f < 2048; f += 256) {
        int kt = f >> 6, lane = f & 63;
        int kb = kt * 16 + ((lane >> 5) << 3);
        int c = lane & 31;
        union { unsigned char b[8]; i64 v; } u;
        #pragma unroll
        for (int j = 0; j < 8; ++j) u.b[j] = s[(kb + j) * 32 + c];
        wot8[(size_t)g * 2048 + f] = u.v;
    }
}

// ---------------------------------------------------------------------------
// wcell_prep (R11/R12-verified): Wi/Wh -> bf16 B-frag order block-packed.
// ---------------------------------------------------------------------------
__global__ __launch_bounds__(256) void wcell_prep_kernel(
    const float* __restrict__ Wi, const float* __restrict__ Wh,
    unsigned short* __restrict__ wcell) {
    __shared__ unsigned short s[512 * 32];     // [kl][lc] 32 KB
    int cb = blockIdx.x >> 1;
    int half = blockIdx.x & 1;
    const float* Wsrc = half ? Wh : Wi;
    int tid = threadIdx.x;
    int lc = tid & 31;
    int gcol = (lc >> 3) * 512 + cb * 8 + (lc & 7);
    int k0 = tid >> 5;
    for (int kl = k0; kl < 512; kl += 8)
        s[kl * 32 + lc] = f2bf(Wsrc[(size_t)kl * G4 + gcol]);
    __syncthreads();
    bf16x8* out8 = (bf16x8*)wcell;
    for (int f = tid; f < 2048; f += 256) {
        int ktl = f >> 6, lane = f & 63;
        int kb = ktl * 16 + ((lane >> 5) << 3);
        int c = lane & 31;
        bf16x8 v;
        #pragma unroll
        for (int j = 0; j < 8; ++j) v[j] = (short)s[(kb + j) * 32 + c];
        out8[((size_t)cb * 64 + half * 32 + ktl) * 64 + lane] = v;
    }
}

// ---------------------------------------------------------------------------
// cell_mfma3: 64 blocks x 1024 thr (16 waves). R12-proven structure, 250
// slots. PHASE A: tokens (+CE in block 0). PHASE B: wave wv = 4-MFMA chain
// over wcell. PHASE C: gate math; writes h_bf (cell recurrence) + h_f8
// (logits input, scaled SH).
// ---------------------------------------------------------------------------
__global__ __launch_bounds__(1024) void cell_mfma3_kernel(
    const float* __restrict__ emb, const int* __restrict__ labels,
    const void* __restrict__ coin, const int* __restrict__ flag,
    const unsigned short* __restrict__ wcell, const float* __restrict__ bias,
    float* __restrict__ cst, unsigned short* __restrict__ hbf,
    unsigned char* __restrict__ hf8,
    const float* __restrict__ part, float* __restrict__ ce_acc, int t) {
    __shared__ float sg[16][32][32];    // 64 KB [wave][row][lc]
    __shared__ float st[32][33];        // combined gates
    __shared__ int s_tok[32];
    int tid = threadIdx.x;
    int cb = blockIdx.x;
    int lane = tid & 63, wv = tid >> 6;

    // ---- PHASE A ----
    if (t == 0) {
        if (tid < 32) s_tok[tid] = 1;            // START
    } else {
        int row = tid >> 5, slot = tid & 31;
        int tm1 = t - 1;
        float m = -3.0e38f; int mi = 0;
        for (int ib = slot; ib < NLB; ib += 32) {
            int e = row * 256 + ib;
            float pm = part[e];
            int pi = __float_as_int(part[2 * PSTRIDE + e]);
            if (pm > m || (pm == m && pi < mi)) { m = pm; mi = pi; }
        }
        #pragma unroll
        for (int d = 1; d < 32; d <<= 1) {
            float om = __shfl_xor(m, d);
            int omi = __shfl_xor(mi, d);
            if (om > m || (om == m && omi < mi)) { m = om; mi = omi; }
        }
        if (slot == 0) {
            int lab = labels[row * TLEN + tm1];
            int cn = (*flag) ? (int)((const unsigned char*)coin)[row * TLEN + tm1]
                             : ((const int*)coin)[row * TLEN + tm1];
            s_tok[row] = cn ? mi : lab;
        }
        if (cb == 0) {
            float M = -3.0e38f, S = 0.f, L = -INFINITY;
            for (int ib = slot; ib < NLB; ib += 32) {
                int e = row * 256 + ib;
                float pm = part[e], ps = part[PSTRIDE + e];
                float nM = fmaxf(M, pm);
                S = S * expf(M - nM) + ps * expf(pm - nM);
                M = nM;
                L = fmaxf(L, part[3 * PSTRIDE + e]);
            }
            #pragma unroll
            for (int d = 1; d < 32; d <<= 1) {
                float oM = __shfl_xor(M, d), oS = __shfl_xor(S, d);
                float nM = fmaxf(M, oM);
                S = S * expf(M - nM) + oS * expf(oM - nM);
                M = nM;
                L = fmaxf(L, __shfl_xor(L, d));
            }
            if (slot == 0) ce_acc[row] += (M + logf(S)) - L;
        }
    }
    __syncthreads();

    // ---- PHASE B ----
    int r = lane & 31;
    int ksub = (lane >> 5) << 3;       // 0 or 8
    const bf16x8* wp = (const bf16x8*)wcell + ((size_t)cb * 64 + wv * 4) * 64 + lane;

    f32x16 acc = {};
    if (wv < 8) {
        const float* ebase = emb + (size_t)s_tok[r] * EMBD;
        #pragma unroll
        for (int i = 0; i < 4; ++i) {
            int k = (wv * 4 + i) * 16 + ksub;
            float4 e0 = *(const float4*)(ebase + k);
            float4 e1 = *(const float4*)(ebase + k + 4);
            bf16x8 a;
            a[0] = (short)f2bf(e0.x); a[1] = (short)f2bf(e0.y);
            a[2] = (short)f2bf(e0.z); a[3] = (short)f2bf(e0.w);
            a[4] = (short)f2bf(e1.x); a[5] = (short)f2bf(e1.y);
            a[6] = (short)f2bf(e1.z); a[7] = (short)f2bf(e1.w);
            acc = __builtin_amdgcn_mfma_f32_32x32x16_bf16(a, wp[i * 64], acc, 0, 0, 0);
        }
    } else {
        #pragma unroll
        for (int i = 0; i < 4; ++i) {
            int k = (wv * 4 + i) * 16 + ksub - 512;
            bf16x8 a = *(const bf16x8*)&hbf[r * HIDD + k];
            acc = __builtin_amdgcn_mfma_f32_32x32x16_bf16(a, wp[i * 64], acc, 0, 0, 0);
        }
    }

    int half = lane >> 5;
    #pragma unroll
    for (int reg = 0; reg < 16; ++reg) {
        int row = (reg & 3) + 8 * (reg >> 2) + 4 * half;
        sg[wv][row][lane & 31] = acc[reg];
    }
    __syncthreads();

    {
        int row = tid >> 5, lc = tid & 31;
        float s = 0.f;
        #pragma unroll
        for (int w = 0; w < 16; ++w) s += sg[w][row][lc];
        st[row][lc] = s;
    }
    __syncthreads();

    // ---- PHASE C ----
    if (tid < 256) {
        int rr = tid >> 3, jj = tid & 7;
        int jh = cb * 8 + jj;
        float i_ = bias[jh]        + st[rr][jj];
        float f_ = bias[jh + 512]  + st[rr][jj + 8];
        float g_ = bias[jh + 1024] + st[rr][jj + 16];
        float o_ = bias[jh + 1536] + st[rr][jj + 24];
        int idx = rr * HIDD + jh;
        float ci = cst[idx];
        float cn = sigmoidf_(f_) * ci + sigmoidf_(i_) * tanhf(g_);
        float hn = sigmoidf_(o_) * tanhf(cn);
        cst[idx] = cn;
        hbf[idx] = f2bf(hn);
        hf8[idx] = f2e4m3(hn * SH);
    }
}

// ---------------------------------------------------------------------------
// logits_fp8: 250 blocks x 256 thr (R8-proven shape). Wave = col-group
// g = blk*4+wv, K=512 via 2x16 fp8 MFMA chains (K=16 each). h_f8 staged in
// LDS frag-order (16 KB). Logit = acc*INV_SWH + bo. Epilogue & partials as
// R8: part slot blockIdx (stride 256).
// C/D layout: col=lane&31, row=(reg&3)+8*(reg>>2)+4*(lane>>5).
// ---------------------------------------------------------------------------
__global__ __launch_bounds__(256) void logits_fp8_kernel(
    const i64* __restrict__ wot8, const unsigned char* __restrict__ h_f8,
    const float* __restrict__ bo, const int* __restrict__ labels,
    float* __restrict__ part, int t) {
    __shared__ __align__(16) i64 s_h[2048];    // 16 KB frag-order
    __shared__ int s_lab[32];
    __shared__ float s_pm[4][32], s_ps[4][32], s_pl[4][32], s_pst[4][32];
    __shared__ int s_pi[4][32];
    int tid = threadIdx.x;
    int lane = tid & 63, wv = tid >> 6;

    for (int f = tid; f < 2048; f += 256) {
        int kt = f >> 6, ln = f & 63;
        int row = ln & 31, kb = kt * 16 + ((ln >> 5) << 3);
        s_h[f] = *(const i64*)&h_f8[row * 512 + kb];
    }
    if (tid < 32) s_lab[tid] = labels[tid * TLEN + t];
    __syncthreads();

    int g = blockIdx.x * 4 + wv;                 // col-group 0..999
    const i64* wp = wot8 + (size_t)g * 2048 + lane;

    f32x16 acc0 = {}, acc1 = {};
    #pragma unroll 4
    for (int kt = 0; kt < 16; ++kt) {
        acc0 = __builtin_amdgcn_mfma_f32_32x32x16_fp8_fp8(
            s_h[kt * 64 + lane], wp[kt * 64], acc0, 0, 0, 0);
        acc1 = __builtin_amdgcn_mfma_f32_32x32x16_fp8_fp8(
            s_h[(kt + 16) * 64 + lane], wp[(kt + 16) * 64], acc1, 0, 0, 0);
    }

    int half = lane >> 5;
    int colw = lane & 31;
    int col = g * 32 + colw;
    float bq = bo[col];

    #pragma unroll
    for (int reg = 0; reg < 16; ++reg) {
        int row = (reg & 3) + 8 * (reg >> 2) + 4 * half;
        float v = (acc0[reg] + acc1[reg]) * INV_SWH + bq;
        float m = v; int mi = col;
        #pragma unroll
        for (int d = 1; d < 32; d <<= 1) {
            float om = __shfl_xor(m, d);
            int omi = __shfl_xor(mi, d);
            if (om > m || (om == m && omi < mi)) { m = om; mi = omi; }
        }
        float e = expf(v - m), ssum = e;
        #pragma unroll
        for (int d = 1; d < 32; d <<= 1) ssum += __shfl_xor(ssum, d);
        int labc = s_lab[row];
        float lv = __shfl(v, (labc & 31) + (half << 5));
        if ((labc >> 5) != g) lv = -INFINITY;
        float sv = __shfl(v, 2 + (half << 5));   // STOP = 2
        if (g != 0) sv = -INFINITY;
        if (colw == 0) {
            s_pm[wv][row] = m; s_ps[wv][row] = ssum; s_pi[wv][row] = mi;
            s_pl[wv][row] = lv; s_pst[wv][row] = sv;
        }
    }
    __syncthreads();

    if (tid < 32) {
        int row = tid;
        float M = s_pm[0][row], S = s_ps[0][row];
        int MI = s_pi[0][row];
        float L = s_pl[0][row], ST = s_pst[0][row];
        #pragma unroll
        for (int w = 1; w < 4; ++w) {
            float pm = s_pm[w][row], ps = s_ps[w][row];
            int pi = s_pi[w][row];
            float nM = fmaxf(M, pm);
            S = S * expf(M - nM) + ps * expf(pm - nM);
            if (pm > M || (pm == M && pi < MI)) MI = pi;
            M = nM;
            L = fmaxf(L, s_pl[w][row]);
            ST = fmaxf(ST, s_pst[w][row]);
        }
        int e0 = row * 256 + blockIdx.x;
        part[e0] = M;
        part[PSTRIDE + e0] = S;
        part[2 * PSTRIDE + e0] = __int_as_float(MI);
        part[3 * PSTRIDE + e0] = L;
        part[4 * PSTRIDE + e0] = ST;
    }
}

// ---------------------------------------------------------------------------
// finalize5: STOP-step CE from part(t=32); out = (ce_acc + final)/32
// ---------------------------------------------------------------------------
__global__ __launch_bounds__(256) void finalize5_kernel(
    const float* __restrict__ part, const float* __restrict__ ce_acc,
    float* __restrict__ out) {
    __shared__ float s_ce[32];
    int tid = threadIdx.x;
    int row = tid >> 3, slot = tid & 7;
    float M = -3.0e38f, S = 0.f, ST = -INFINITY;
    for (int ib = slot; ib < NLB; ib += 8) {
        int e = row * 256 + ib;
        float pm = part[e], ps = part[PSTRIDE + e];
        float nM = fmaxf(M, pm);
        S = S * expf(M - nM) + ps * expf(pm - nM);
        M = nM;
        ST = fmaxf(ST, part[4 * PSTRIDE + e]);
    }
    #pragma unroll
    for (int d = 1; d < 8; d <<= 1) {
        float oM = __shfl_xor(M, d), oS = __shfl_xor(S, d);
        float nM = fmaxf(M, oM);
        S = S * expf(M - nM) + oS * expf(oM - nM);
        M = nM;
        ST = fmaxf(ST, __shfl_xor(ST, d));
    }
    if (slot == 0) s_ce[row] = ce_acc[row] + (M + logf(S)) - ST;
    __syncthreads();
    if (tid == 0) {
        float tot = 0.f;
        for (int r = 0; r < 32; ++r) tot += s_ce[r];
        *out = tot / 32.f;
    }
}

// ===========================================================================
extern "C" void kernel_launch(void* const* d_in, const int* in_sizes, int n_in,
                              void* d_out, int out_size, void* d_ws, size_t ws_size,
                              hipStream_t stream) {
    const float* x      = (const float*)d_in[0];
    const int*   labels = (const int*)  d_in[1];
    const void*  coin   =               d_in[2];
    const float* emb    = (const float*)d_in[3];
    const float* Wi     = (const float*)d_in[4];
    const float* Wh     = (const float*)d_in[5];
    const float* b      = (const float*)d_in[6];
    const float* Wo     = (const float*)d_in[7];
    const float* bo     = (const float*)d_in[8];

    float* ws     = (float*)d_ws;
    float* cst    = ws;                        // 16384
    unsigned short* h_bf = (unsigned short*)(ws + 16384);   // 8192 floats
    unsigned char*  h_f8 = (unsigned char*)(ws + 24576);    // 4096 floats
    float* part   = ws + 28672;                // 5*8192 = 40960
    float* ce_acc = ws + 69632;                // 32
    int*   flag   = (int*)(ws + 69664);        // 1 (+pad)
    unsigned short* wcell = (unsigned short*)(ws + 69696);  // 1048576 floats
    i64*   wot8   = (i64*)(ws + 69696 + 1048576);           // 4096000 floats
    float* outp   = (float*)d_out;

    wot8_prep_kernel<<<NGRP, 256, 0, stream>>>(Wo, wot8);
    wcell_prep_kernel<<<128, 256, 0, stream>>>(Wi, Wh, wcell);
    init5_kernel<<<1, 256, 0, stream>>>(x, coin, cst, h_bf, h_f8, ce_acc, flag);

    for (int t = 0; t < 33; ++t) {
        int tt = (t < 32) ? t : 0;
        cell_mfma3_kernel<<<64, 1024, 0, stream>>>(emb, labels, coin, flag,
                                                   wcell, b, cst, h_bf, h_f8,
                                                   part, ce_acc, t);
        logits_fp8_kernel<<<NLB, 256, 0, stream>>>(wot8, h_f8, bo, labels,
                                                   part, tt);
    }
    finalize5_kernel<<<1, 256, 0, stream>>>(part, ce_acc, outp);
}

// Round 14
// 1233.913 us; speedup vs baseline: 2.6356x; 1.0136x over previous
//
#include <hip/hip_runtime.h>
#include <math.h>

#define VOCABSZ 32000
#define EMBD 512
#define HIDD 512
#define BSZ 32
#define TLEN 32
#define G4 2048
#define NGRP 1000            // wot col-groups of 32
#define NLB 250              // logits blocks / partial slots
#define PSTRIDE 8192         // part SoA stride (32 rows * 256 slots)
#define SW 256.0f            // Wo fp8 scale
#define SH 16.0f             // h fp8 scale
#define INV_SWH (1.0f / (SW * SH))

using bf16x8 = __attribute__((ext_vector_type(8))) short;
using f32x16 = __attribute__((ext_vector_type(16))) float;
typedef long long i64;

__device__ __forceinline__ float sigmoidf_(float x) { return 1.f / (1.f + expf(-x)); }
__device__ __forceinline__ unsigned short f2bf(float f) {
    unsigned u = __float_as_uint(f);
    return (unsigned short)((u + 0x7fffu + ((u >> 16) & 1u)) >> 16);   // RNE
}
// float -> OCP e4m3fn, RNE, FTZ for |x| < 2^-6 (negligible for our data)
__device__ __forceinline__ unsigned char f2e4m3(float f) {
    unsigned u = __float_as_uint(f);
    unsigned s = (u >> 24) & 0x80u;
    int e = (int)((u >> 23) & 0xffu);
    unsigned m = u & 0x7fffffu;
    int ee = e - 120;                    // e4m3 biased exponent
    if (ee >= 16) return (unsigned char)(s | 0x7E);   // saturate to 448
    if (ee <= 0) return (unsigned char)s;             // FTZ
    unsigned r = m + 0x7FFFFu + ((m >> 20) & 1u);     // RNE to 3 mant bits
    if (r & 0x800000u) { ee += 1; r = 0; if (ee >= 16) return (unsigned char)(s | 0x7E); }
    unsigned mant = (r >> 20) & 7u;
    if (ee == 15 && mant == 7u) return (unsigned char)(s | 0x7E);  // avoid NaN enc
    return (unsigned char)(s | (unsigned)(ee << 3) | mant);
}

// ---------------------------------------------------------------------------
// init6: cst <- 0, h_bf <- bf16(x), h_f8 <- e4m3(x*SH), ce_acc <- 0,
// PARALLEL coin probe (256 threads, 1 word each; benign-race LDS flag).
// ---------------------------------------------------------------------------
__global__ void init6_kernel(const float* __restrict__ x,
                             const void* __restrict__ coin,
                             float* __restrict__ cst,
                             unsigned short* __restrict__ hbf,
                             unsigned char* __restrict__ hf8,
                             float* __restrict__ ce_acc, int* __restrict__ flag) {
    __shared__ int s_f;
    int tid = threadIdx.x;
    if (tid == 0) s_f = 0;
    __syncthreads();
    // coin dtype probe: uint8 bools pack to words like 0x00010001 (>1).
    // First 256 words = 1KB, within bounds for both layouts.
    if (tid < 256 && ((const unsigned int*)coin)[tid] > 1u) s_f = 1;
    __syncthreads();
    if (tid == 0) *flag = s_f;
    if (tid < 32) ce_acc[tid] = 0.f;
    for (int i = tid; i < BSZ * HIDD; i += blockDim.x) {
        float v = x[i];
        cst[i] = 0.f;
        hbf[i] = f2bf(v);
        hf8[i] = f2e4m3(v * SH);
    }
}

// ---------------------------------------------------------------------------
// emb_prep: emb [32000][512] fp32 -> bf16 same layout (vectorized).
// 2048 blocks x 256 thr x 8 elems.
// ---------------------------------------------------------------------------
__global__ __launch_bounds__(256) void emb_prep_kernel(
    const float* __restrict__ emb, unsigned short* __restrict__ embbf) {
    size_t i8 = ((size_t)blockIdx.x * 256 + threadIdx.x) * 8;
    float4 a = *(const float4*)&emb[i8];
    float4 b = *(const float4*)&emb[i8 + 4];
    bf16x8 v;
    v[0] = (short)f2bf(a.x); v[1] = (short)f2bf(a.y);
    v[2] = (short)f2bf(a.z); v[3] = (short)f2bf(a.w);
    v[4] = (short)f2bf(b.x); v[5] = (short)f2bf(b.y);
    v[6] = (short)f2bf(b.z); v[7] = (short)f2bf(b.w);
    *(bf16x8*)&embbf[i8] = v;
}

// ---------------------------------------------------------------------------
// wot8_prep (R13-verified): Wo -> e4m3(Wo*SW) in MFMA B-frag order.
// ---------------------------------------------------------------------------
__global__ __launch_bounds__(256) void wot8_prep_kernel(
    const float* __restrict__ Wo, i64* __restrict__ wot8) {
    __shared__ unsigned char s[512 * 32];      // [k][col] 16 KB
    int g = blockIdx.x;
    int tid = threadIdx.x;
    int col = tid & 31;
    int k0 = tid >> 5;
    for (int kk = k0; kk < 512; kk += 8)
        s[kk * 32 + col] = f2e4m3(Wo[(size_t)kk * VOCABSZ + g * 32 + col] * SW);
    __syncthreads();
    for (int f = tid; f < 2048; f += 256) {
        int kt = f >> 6, lane = f & 63;
        int kb = kt * 16 + ((lane >> 5) << 3);
        int c = lane & 31;
        union { unsigned char b[8]; i64 v; } u;
        #pragma unroll
        for (int j = 0; j < 8; ++j) u.b[j] = s[(kb + j) * 32 + c];
        wot8[(size_t)g * 2048 + f] = u.v;
    }
}

// ---------------------------------------------------------------------------
// wcell_prep (R11/R12/R13-verified): Wi/Wh -> bf16 B-frag order block-packed.
// ---------------------------------------------------------------------------
__global__ __launch_bounds__(256) void wcell_prep_kernel(
    const float* __restrict__ Wi, const float* __restrict__ Wh,
    unsigned short* __restrict__ wcell) {
    __shared__ unsigned short s[512 * 32];     // [kl][lc] 32 KB
    int cb = blockIdx.x >> 1;
    int half = blockIdx.x & 1;
    const float* Wsrc = half ? Wh : Wi;
    int tid = threadIdx.x;
    int lc = tid & 31;
    int gcol = (lc >> 3) * 512 + cb * 8 + (lc & 7);
    int k0 = tid >> 5;
    for (int kl = k0; kl < 512; kl += 8)
        s[kl * 32 + lc] = f2bf(Wsrc[(size_t)kl * G4 + gcol]);
    __syncthreads();
    bf16x8* out8 = (bf16x8*)wcell;
    for (int f = tid; f < 2048; f += 256) {
        int ktl = f >> 6, lane = f & 63;
        int kb = ktl * 16 + ((lane >> 5) << 3);
        int c = lane & 31;
        bf16x8 v;
        #pragma unroll
        for (int j = 0; j < 8; ++j) v[j] = (short)s[(kb + j) * 32 + c];
        out8[((size_t)cb * 64 + half * 32 + ktl) * 64 + lane] = v;
    }
}

// ---------------------------------------------------------------------------
// cell_mfma4: 64 blocks x 1024 thr (16 waves). R13-proven structure; the
// emb-sourced A-frags now read bf16 directly from embbf (16B/lane, no cvt)
// when embbf != null, else fp32-gather+cvt fallback.
// ---------------------------------------------------------------------------
__global__ __launch_bounds__(1024) void cell_mfma4_kernel(
    const float* __restrict__ emb, const unsigned short* __restrict__ embbf,
    const int* __restrict__ labels,
    const void* __restrict__ coin, const int* __restrict__ flag,
    const unsigned short* __restrict__ wcell, const float* __restrict__ bias,
    float* __restrict__ cst, unsigned short* __restrict__ hbf,
    unsigned char* __restrict__ hf8,
    const float* __restrict__ part, float* __restrict__ ce_acc, int t) {
    __shared__ float sg[16][32][32];    // 64 KB [wave][row][lc]
    __shared__ float st[32][33];        // combined gates
    __shared__ int s_tok[32];
    int tid = threadIdx.x;
    int cb = blockIdx.x;
    int lane = tid & 63, wv = tid >> 6;

    // ---- PHASE A ----
    if (t == 0) {
        if (tid < 32) s_tok[tid] = 1;            // START
    } else {
        int row = tid >> 5, slot = tid & 31;
        int tm1 = t - 1;
        float m = -3.0e38f; int mi = 0;
        for (int ib = slot; ib < NLB; ib += 32) {
            int e = row * 256 + ib;
            float pm = part[e];
            int pi = __float_as_int(part[2 * PSTRIDE + e]);
            if (pm > m || (pm == m && pi < mi)) { m = pm; mi = pi; }
        }
        #pragma unroll
        for (int d = 1; d < 32; d <<= 1) {
            float om = __shfl_xor(m, d);
            int omi = __shfl_xor(mi, d);
            if (om > m || (om == m && omi < mi)) { m = om; mi = omi; }
        }
        if (slot == 0) {
            int lab = labels[row * TLEN + tm1];
            int cn = (*flag) ? (int)((const unsigned char*)coin)[row * TLEN + tm1]
                             : ((const int*)coin)[row * TLEN + tm1];
            s_tok[row] = cn ? mi : lab;
        }
        if (cb == 0) {
            float M = -3.0e38f, S = 0.f, L = -INFINITY;
            for (int ib = slot; ib < NLB; ib += 32) {
                int e = row * 256 + ib;
                float pm = part[e], ps = part[PSTRIDE + e];
                float nM = fmaxf(M, pm);
                S = S * expf(M - nM) + ps * expf(pm - nM);
                M = nM;
                L = fmaxf(L, part[3 * PSTRIDE + e]);
            }
            #pragma unroll
            for (int d = 1; d < 32; d <<= 1) {
                float oM = __shfl_xor(M, d), oS = __shfl_xor(S, d);
                float nM = fmaxf(M, oM);
                S = S * expf(M - nM) + oS * expf(oM - nM);
                M = nM;
                L = fmaxf(L, __shfl_xor(L, d));
            }
            if (slot == 0) ce_acc[row] += (M + logf(S)) - L;
        }
    }
    __syncthreads();

    // ---- PHASE B ----
    int r = lane & 31;
    int ksub = (lane >> 5) << 3;       // 0 or 8
    const bf16x8* wp = (const bf16x8*)wcell + ((size_t)cb * 64 + wv * 4) * 64 + lane;

    f32x16 acc = {};
    if (wv < 8) {
        int tok = s_tok[r];
        if (embbf) {
            const unsigned short* eb = embbf + (size_t)tok * EMBD;
            #pragma unroll
            for (int i = 0; i < 4; ++i) {
                int k = (wv * 4 + i) * 16 + ksub;
                bf16x8 a = *(const bf16x8*)&eb[k];
                acc = __builtin_amdgcn_mfma_f32_32x32x16_bf16(a, wp[i * 64], acc, 0, 0, 0);
            }
        } else {
            const float* ebase = emb + (size_t)tok * EMBD;
            #pragma unroll
            for (int i = 0; i < 4; ++i) {
                int k = (wv * 4 + i) * 16 + ksub;
                float4 e0 = *(const float4*)(ebase + k);
                float4 e1 = *(const float4*)(ebase + k + 4);
                bf16x8 a;
                a[0] = (short)f2bf(e0.x); a[1] = (short)f2bf(e0.y);
                a[2] = (short)f2bf(e0.z); a[3] = (short)f2bf(e0.w);
                a[4] = (short)f2bf(e1.x); a[5] = (short)f2bf(e1.y);
                a[6] = (short)f2bf(e1.z); a[7] = (short)f2bf(e1.w);
                acc = __builtin_amdgcn_mfma_f32_32x32x16_bf16(a, wp[i * 64], acc, 0, 0, 0);
            }
        }
    } else {
        #pragma unroll
        for (int i = 0; i < 4; ++i) {
            int k = (wv * 4 + i) * 16 + ksub - 512;
            bf16x8 a = *(const bf16x8*)&hbf[r * HIDD + k];
            acc = __builtin_amdgcn_mfma_f32_32x32x16_bf16(a, wp[i * 64], acc, 0, 0, 0);
        }
    }

    int half = lane >> 5;
    #pragma unroll
    for (int reg = 0; reg < 16; ++reg) {
        int row = (reg & 3) + 8 * (reg >> 2) + 4 * half;
        sg[wv][row][lane & 31] = acc[reg];
    }
    __syncthreads();

    {
        int row = tid >> 5, lc = tid & 31;
        float s = 0.f;
        #pragma unroll
        for (int w = 0; w < 16; ++w) s += sg[w][row][lc];
        st[row][lc] = s;
    }
    __syncthreads();

    // ---- PHASE C ----
    if (tid < 256) {
        int rr = tid >> 3, jj = tid & 7;
        int jh = cb * 8 + jj;
        float i_ = bias[jh]        + st[rr][jj];
        float f_ = bias[jh + 512]  + st[rr][jj + 8];
        float g_ = bias[jh + 1024] + st[rr][jj + 16];
        float o_ = bias[jh + 1536] + st[rr][jj + 24];
        int idx = rr * HIDD + jh;
        float ci = cst[idx];
        float cn = sigmoidf_(f_) * ci + sigmoidf_(i_) * tanhf(g_);
        float hn = sigmoidf_(o_) * tanhf(cn);
        cst[idx] = cn;
        hbf[idx] = f2bf(hn);
        hf8[idx] = f2e4m3(hn * SH);
    }
}

// ---------------------------------------------------------------------------
// logits_fp8 (R13-verified): 250 blocks x 256 thr; fp8 MFMA, K=512;
// partials -> part slot blockIdx.
// ---------------------------------------------------------------------------
__global__ __launch_bounds__(256) void logits_fp8_kernel(
    const i64* __restrict__ wot8, const unsigned char* __restrict__ h_f8,
    const float* __restrict__ bo, const int* __restrict__ labels,
    float* __restrict__ part, int t) {
    __shared__ __align__(16) i64 s_h[2048];    // 16 KB frag-order
    __shared__ int s_lab[32];
    __shared__ float s_pm[4][32], s_ps[4][32], s_pl[4][32], s_pst[4][32];
    __shared__ int s_pi[4][32];
    int tid = threadIdx.x;
    int lane = tid & 63, wv = tid >> 6;

    for (int f = tid; f < 2048; f += 256) {
        int kt = f >> 6, ln = f & 63;
        int row = ln & 31, kb = kt * 16 + ((ln >> 5) << 3);
        s_h[f] = *(const i64*)&h_f8[row * 512 + kb];
    }
    if (tid < 32) s_lab[tid] = labels[tid * TLEN + t];
    __syncthreads();

    int g = blockIdx.x * 4 + wv;                 // col-group 0..999
    const i64* wp = wot8 + (size_t)g * 2048 + lane;

    f32x16 acc0 = {}, acc1 = {};
    #pragma unroll 4
    for (int kt = 0; kt < 16; ++kt) {
        acc0 = __builtin_amdgcn_mfma_f32_32x32x16_fp8_fp8(
            s_h[kt * 64 + lane], wp[kt * 64], acc0, 0, 0, 0);
        acc1 = __builtin_amdgcn_mfma_f32_32x32x16_fp8_fp8(
            s_h[(kt + 16) * 64 + lane], wp[(kt + 16) * 64], acc1, 0, 0, 0);
    }

    int half = lane >> 5;
    int colw = lane & 31;
    int col = g * 32 + colw;
    float bq = bo[col];

    #pragma unroll
    for (int reg = 0; reg < 16; ++reg) {
        int row = (reg & 3) + 8 * (reg >> 2) + 4 * half;
        float v = (acc0[reg] + acc1[reg]) * INV_SWH + bq;
        float m = v; int mi = col;
        #pragma unroll
        for (int d = 1; d < 32; d <<= 1) {
            float om = __shfl_xor(m, d);
            int omi = __shfl_xor(mi, d);
            if (om > m || (om == m && omi < mi)) { m = om; mi = omi; }
        }
        float e = expf(v - m), ssum = e;
        #pragma unroll
        for (int d = 1; d < 32; d <<= 1) ssum += __shfl_xor(ssum, d);
        int labc = s_lab[row];
        float lv = __shfl(v, (labc & 31) + (half << 5));
        if ((labc >> 5) != g) lv = -INFINITY;
        float sv = __shfl(v, 2 + (half << 5));   // STOP = 2
        if (g != 0) sv = -INFINITY;
        if (colw == 0) {
            s_pm[wv][row] = m; s_ps[wv][row] = ssum; s_pi[wv][row] = mi;
            s_pl[wv][row] = lv; s_pst[wv][row] = sv;
        }
    }
    __syncthreads();

    if (tid < 32) {
        int row = tid;
        float M = s_pm[0][row], S = s_ps[0][row];
        int MI = s_pi[0][row];
        float L = s_pl[0][row], ST = s_pst[0][row];
        #pragma unroll
        for (int w = 1; w < 4; ++w) {
            float pm = s_pm[w][row], ps = s_ps[w][row];
            int pi = s_pi[w][row];
            float nM = fmaxf(M, pm);
            S = S * expf(M - nM) + ps * expf(pm - nM);
            if (pm > M || (pm == M && pi < MI)) MI = pi;
            M = nM;
            L = fmaxf(L, s_pl[w][row]);
            ST = fmaxf(ST, s_pst[w][row]);
        }
        int e0 = row * 256 + blockIdx.x;
        part[e0] = M;
        part[PSTRIDE + e0] = S;
        part[2 * PSTRIDE + e0] = __int_as_float(MI);
        part[3 * PSTRIDE + e0] = L;
        part[4 * PSTRIDE + e0] = ST;
    }
}

// ---------------------------------------------------------------------------
// finalize5 (R13-verified): STOP-step CE; out = (ce_acc + final)/32
// ---------------------------------------------------------------------------
__global__ __launch_bounds__(256) void finalize5_kernel(
    const float* __restrict__ part, const float* __restrict__ ce_acc,
    float* __restrict__ out) {
    __shared__ float s_ce[32];
    int tid = threadIdx.x;
    int row = tid >> 3, slot = tid & 7;
    float M = -3.0e38f, S = 0.f, ST = -INFINITY;
    for (int ib = slot; ib < NLB; ib += 8) {
        int e = row * 256 + ib;
        float pm = part[e], ps = part[PSTRIDE + e];
        float nM = fmaxf(M, pm);
        S = S * expf(M - nM) + ps * expf(pm - nM);
        M = nM;
        ST = fmaxf(ST, part[4 * PSTRIDE + e]);
    }
    #pragma unroll
    for (int d = 1; d < 8; d <<= 1) {
        float oM = __shfl_xor(M, d), oS = __shfl_xor(S, d);
        float nM = fmaxf(M, oM);
        S = S * expf(M - nM) + oS * expf(oM - nM);
        M = nM;
        ST = fmaxf(ST, __shfl_xor(ST, d));
    }
    if (slot == 0) s_ce[row] = ce_acc[row] + (M + logf(S)) - ST;
    __syncthreads();
    if (tid == 0) {
        float tot = 0.f;
        for (int r = 0; r < 32; ++r) tot += s_ce[r];
        *out = tot / 32.f;
    }
}

// ===========================================================================
extern "C" void kernel_launch(void* const* d_in, const int* in_sizes, int n_in,
                              void* d_out, int out_size, void* d_ws, size_t ws_size,
                              hipStream_t stream) {
    const float* x      = (const float*)d_in[0];
    const int*   labels = (const int*)  d_in[1];
    const void*  coin   =               d_in[2];
    const float* emb    = (const float*)d_in[3];
    const float* Wi     = (const float*)d_in[4];
    const float* Wh     = (const float*)d_in[5];
    const float* b      = (const float*)d_in[6];
    const float* Wo     = (const float*)d_in[7];
    const float* bo     = (const float*)d_in[8];

    float* ws     = (float*)d_ws;
    float* cst    = ws;                        // 16384
    unsigned short* h_bf = (unsigned short*)(ws + 16384);   // 8192 floats
    unsigned char*  h_f8 = (unsigned char*)(ws + 24576);    // 4096 floats
    float* part   = ws + 28672;                // 5*8192 = 40960
    float* ce_acc = ws + 69632;                // 32
    int*   flag   = (int*)(ws + 69664);        // 1 (+pad)
    unsigned short* wcell = (unsigned short*)(ws + 69696);  // 1048576 floats
    i64*   wot8   = (i64*)(ws + 69696 + 1048576);           // 4096000 floats
    unsigned short* embbf = (unsigned short*)(ws + 69696 + 1048576 + 4096000); // 8192000 floats
    float* outp   = (float*)d_out;

    size_t need_emb = (size_t)(69696 + 1048576 + 4096000 + 8192000) * 4;
    const unsigned short* embbf_use = (ws_size >= need_emb) ? embbf : (const unsigned short*)0;

    wot8_prep_kernel<<<NGRP, 256, 0, stream>>>(Wo, wot8);
    wcell_prep_kernel<<<128, 256, 0, stream>>>(Wi, Wh, wcell);
    if (embbf_use)
        emb_prep_kernel<<<VOCABSZ * EMBD / 2048, 256, 0, stream>>>(emb, embbf);
    init6_kernel<<<1, 256, 0, stream>>>(x, coin, cst, h_bf, h_f8, ce_acc, flag);

    for (int t = 0; t < 33; ++t) {
        int tt = (t < 32) ? t : 0;
        cell_mfma4_kernel<<<64, 1024, 0, stream>>>(emb, embbf_use, labels, coin,
                                                   flag, wcell, b, cst, h_bf,
                                                   h_f8, part, ce_acc, t);
        logits_fp8_kernel<<<NLB, 256, 0, stream>>>(wot8, h_f8, bo, labels,
                                                   part, tt);
    }
    finalize5_kernel<<<1, 256, 0, stream>>>(part, ce_acc, outp);
}

// Round 15
// 1072.096 us; speedup vs baseline: 3.0334x; 1.1509x over previous
//
#include <hip/hip_runtime.h>
#include <math.h>

#define VOCABSZ 32000
#define EMBD 512
#define HIDD 512
#define BSZ 32
#define TLEN 32
#define G4 2048
#define NGRP 1000            // wot col-groups of 32
#define NLB 250              // logits blocks / partial slots
#define PSTRIDE 8192         // part SoA stride (32 rows * 256 slots)
#define SW 256.0f            // Wo fp8 scale
#define SH 16.0f             // h fp8 scale
#define INV_SWH (1.0f / (SW * SH))

using bf16x8 = __attribute__((ext_vector_type(8))) short;
using f32x16 = __attribute__((ext_vector_type(16))) float;
typedef long long i64;

__device__ __forceinline__ float sigmoidf_(float x) { return 1.f / (1.f + expf(-x)); }
__device__ __forceinline__ unsigned short f2bf(float f) {
    unsigned u = __float_as_uint(f);
    return (unsigned short)((u + 0x7fffu + ((u >> 16) & 1u)) >> 16);   // RNE
}
// float -> OCP e4m3fn, RNE, FTZ for |x| < 2^-6 (negligible for our data)
__device__ __forceinline__ unsigned char f2e4m3(float f) {
    unsigned u = __float_as_uint(f);
    unsigned s = (u >> 24) & 0x80u;
    int e = (int)((u >> 23) & 0xffu);
    unsigned m = u & 0x7fffffu;
    int ee = e - 120;                    // e4m3 biased exponent
    if (ee >= 16) return (unsigned char)(s | 0x7E);   // saturate to 448
    if (ee <= 0) return (unsigned char)s;             // FTZ
    unsigned r = m + 0x7FFFFu + ((m >> 20) & 1u);     // RNE to 3 mant bits
    if (r & 0x800000u) { ee += 1; r = 0; if (ee >= 16) return (unsigned char)(s | 0x7E); }
    unsigned mant = (r >> 20) & 7u;
    if (ee == 15 && mant == 7u) return (unsigned char)(s | 0x7E);  // avoid NaN enc
    return (unsigned char)(s | (unsigned)(ee << 3) | mant);
}

// ---------------------------------------------------------------------------
// init7: 64 blocks x 256 thr (coalesced, latency-hidden). Block 0: probe +
// ce_acc. One element per thread.
// ---------------------------------------------------------------------------
__global__ __launch_bounds__(256) void init7_kernel(
    const float* __restrict__ x, const void* __restrict__ coin,
    float* __restrict__ cst, unsigned short* __restrict__ hbf,
    unsigned char* __restrict__ hf8,
    float* __restrict__ ce_acc, int* __restrict__ flag) {
    __shared__ int s_f;
    int tid = threadIdx.x;
    int i = blockIdx.x * 256 + tid;
    if (blockIdx.x == 0) {
        if (tid == 0) s_f = 0;
        __syncthreads();
        // coin dtype probe: uint8 bools pack to words like 0x00010001 (>1)
        if (((const unsigned int*)coin)[tid] > 1u) s_f = 1;
        __syncthreads();
        if (tid == 0) *flag = s_f;
        if (tid < 32) ce_acc[tid] = 0.f;
    }
    float v = x[i];
    cst[i] = 0.f;
    hbf[i] = f2bf(v);
    hf8[i] = f2e4m3(v * SH);
}

// ---------------------------------------------------------------------------
// emb_prep (R14): emb fp32 -> bf16 same layout.
// ---------------------------------------------------------------------------
__global__ __launch_bounds__(256) void emb_prep_kernel(
    const float* __restrict__ emb, unsigned short* __restrict__ embbf) {
    size_t i8 = ((size_t)blockIdx.x * 256 + threadIdx.x) * 8;
    float4 a = *(const float4*)&emb[i8];
    float4 b = *(const float4*)&emb[i8 + 4];
    bf16x8 v;
    v[0] = (short)f2bf(a.x); v[1] = (short)f2bf(a.y);
    v[2] = (short)f2bf(a.z); v[3] = (short)f2bf(a.w);
    v[4] = (short)f2bf(b.x); v[5] = (short)f2bf(b.y);
    v[6] = (short)f2bf(b.z); v[7] = (short)f2bf(b.w);
    *(bf16x8*)&embbf[i8] = v;
}

// ---------------------------------------------------------------------------
// wot8_prep: Wo -> e4m3(Wo*SW), MFMA B-frag order, PAIRED-kt layout:
//   flat idx = (kt>>1)*128 + lane*2 + (kt&1)   (per col-group g of 2048 i64)
// so a ulonglong2 load at (ktp*64 + lane) yields {kt=2ktp, kt=2ktp+1}.
// ---------------------------------------------------------------------------
__global__ __launch_bounds__(256) void wot8_prep_kernel(
    const float* __restrict__ Wo, i64* __restrict__ wot8) {
    __shared__ unsigned char s[512 * 32];      // [k][col] 16 KB
    int g = blockIdx.x;
    int tid = threadIdx.x;
    int col = tid & 31;
    int k0 = tid >> 5;
    for (int kk = k0; kk < 512; kk += 8)
        s[kk * 32 + col] = f2e4m3(Wo[(size_t)kk * VOCABSZ + g * 32 + col] * SW);
    __syncthreads();
    for (int f = tid; f < 2048; f += 256) {
        int kt = f >> 6, lane = f & 63;
        int kb = kt * 16 + ((lane >> 5) << 3);
        int c = lane & 31;
        union { unsigned char b[8]; i64 v; } u;
        #pragma unroll
        for (int j = 0; j < 8; ++j) u.b[j] = s[(kb + j) * 32 + c];
        wot8[(size_t)g * 2048 + (kt >> 1) * 128 + lane * 2 + (kt & 1)] = u.v;
    }
}

// ---------------------------------------------------------------------------
// wcell_prep (R11-R14 verified): Wi/Wh -> bf16 B-frag order block-packed.
// ---------------------------------------------------------------------------
__global__ __launch_bounds__(256) void wcell_prep_kernel(
    const float* __restrict__ Wi, const float* __restrict__ Wh,
    unsigned short* __restrict__ wcell) {
    __shared__ unsigned short s[512 * 32];     // [kl][lc] 32 KB
    int cb = blockIdx.x >> 1;
    int half = blockIdx.x & 1;
    const float* Wsrc = half ? Wh : Wi;
    int tid = threadIdx.x;
    int lc = tid & 31;
    int gcol = (lc >> 3) * 512 + cb * 8 + (lc & 7);
    int k0 = tid >> 5;
    for (int kl = k0; kl < 512; kl += 8)
        s[kl * 32 + lc] = f2bf(Wsrc[(size_t)kl * G4 + gcol]);
    __syncthreads();
    bf16x8* out8 = (bf16x8*)wcell;
    for (int f = tid; f < 2048; f += 256) {
        int ktl = f >> 6, lane = f & 63;
        int kb = ktl * 16 + ((lane >> 5) << 3);
        int c = lane & 31;
        bf16x8 v;
        #pragma unroll
        for (int j = 0; j < 8; ++j) v[j] = (short)s[(kb + j) * 32 + c];
        out8[((size_t)cb * 64 + half * 32 + ktl) * 64 + lane] = v;
    }
}

// ---------------------------------------------------------------------------
// cell_mfma4 (R14-verified): 64 blocks x 1024 thr (16 waves).
// ---------------------------------------------------------------------------
__global__ __launch_bounds__(1024) void cell_mfma4_kernel(
    const float* __restrict__ emb, const unsigned short* __restrict__ embbf,
    const int* __restrict__ labels,
    const void* __restrict__ coin, const int* __restrict__ flag,
    const unsigned short* __restrict__ wcell, const float* __restrict__ bias,
    float* __restrict__ cst, unsigned short* __restrict__ hbf,
    unsigned char* __restrict__ hf8,
    const float* __restrict__ part, float* __restrict__ ce_acc, int t) {
    __shared__ float sg[16][32][32];    // 64 KB [wave][row][lc]
    __shared__ float st[32][33];        // combined gates
    __shared__ int s_tok[32];
    int tid = threadIdx.x;
    int cb = blockIdx.x;
    int lane = tid & 63, wv = tid >> 6;

    // ---- PHASE A ----
    if (t == 0) {
        if (tid < 32) s_tok[tid] = 1;            // START
    } else {
        int row = tid >> 5, slot = tid & 31;
        int tm1 = t - 1;
        float m = -3.0e38f; int mi = 0;
        for (int ib = slot; ib < NLB; ib += 32) {
            int e = row * 256 + ib;
            float pm = part[e];
            int pi = __float_as_int(part[2 * PSTRIDE + e]);
            if (pm > m || (pm == m && pi < mi)) { m = pm; mi = pi; }
        }
        #pragma unroll
        for (int d = 1; d < 32; d <<= 1) {
            float om = __shfl_xor(m, d);
            int omi = __shfl_xor(mi, d);
            if (om > m || (om == m && omi < mi)) { m = om; mi = omi; }
        }
        if (slot == 0) {
            int lab = labels[row * TLEN + tm1];
            int cn = (*flag) ? (int)((const unsigned char*)coin)[row * TLEN + tm1]
                             : ((const int*)coin)[row * TLEN + tm1];
            s_tok[row] = cn ? mi : lab;
        }
        if (cb == 0) {
            float M = -3.0e38f, S = 0.f, L = -INFINITY;
            for (int ib = slot; ib < NLB; ib += 32) {
                int e = row * 256 + ib;
                float pm = part[e], ps = part[PSTRIDE + e];
                float nM = fmaxf(M, pm);
                S = S * expf(M - nM) + ps * expf(pm - nM);
                M = nM;
                L = fmaxf(L, part[3 * PSTRIDE + e]);
            }
            #pragma unroll
            for (int d = 1; d < 32; d <<= 1) {
                float oM = __shfl_xor(M, d), oS = __shfl_xor(S, d);
                float nM = fmaxf(M, oM);
                S = S * expf(M - nM) + oS * expf(oM - nM);
                M = nM;
                L = fmaxf(L, __shfl_xor(L, d));
            }
            if (slot == 0) ce_acc[row] += (M + logf(S)) - L;
        }
    }
    __syncthreads();

    // ---- PHASE B ----
    int r = lane & 31;
    int ksub = (lane >> 5) << 3;       // 0 or 8
    const bf16x8* wp = (const bf16x8*)wcell + ((size_t)cb * 64 + wv * 4) * 64 + lane;

    f32x16 acc = {};
    if (wv < 8) {
        int tok = s_tok[r];
        if (embbf) {
            const unsigned short* eb = embbf + (size_t)tok * EMBD;
            #pragma unroll
            for (int i = 0; i < 4; ++i) {
                int k = (wv * 4 + i) * 16 + ksub;
                bf16x8 a = *(const bf16x8*)&eb[k];
                acc = __builtin_amdgcn_mfma_f32_32x32x16_bf16(a, wp[i * 64], acc, 0, 0, 0);
            }
        } else {
            const float* ebase = emb + (size_t)tok * EMBD;
            #pragma unroll
            for (int i = 0; i < 4; ++i) {
                int k = (wv * 4 + i) * 16 + ksub;
                float4 e0 = *(const float4*)(ebase + k);
                float4 e1 = *(const float4*)(ebase + k + 4);
                bf16x8 a;
                a[0] = (short)f2bf(e0.x); a[1] = (short)f2bf(e0.y);
                a[2] = (short)f2bf(e0.z); a[3] = (short)f2bf(e0.w);
                a[4] = (short)f2bf(e1.x); a[5] = (short)f2bf(e1.y);
                a[6] = (short)f2bf(e1.z); a[7] = (short)f2bf(e1.w);
                acc = __builtin_amdgcn_mfma_f32_32x32x16_bf16(a, wp[i * 64], acc, 0, 0, 0);
            }
        }
    } else {
        #pragma unroll
        for (int i = 0; i < 4; ++i) {
            int k = (wv * 4 + i) * 16 + ksub - 512;
            bf16x8 a = *(const bf16x8*)&hbf[r * HIDD + k];
            acc = __builtin_amdgcn_mfma_f32_32x32x16_bf16(a, wp[i * 64], acc, 0, 0, 0);
        }
    }

    int half = lane >> 5;
    #pragma unroll
    for (int reg = 0; reg < 16; ++reg) {
        int row = (reg & 3) + 8 * (reg >> 2) + 4 * half;
        sg[wv][row][lane & 31] = acc[reg];
    }
    __syncthreads();

    {
        int row = tid >> 5, lc = tid & 31;
        float s = 0.f;
        #pragma unroll
        for (int w = 0; w < 16; ++w) s += sg[w][row][lc];
        st[row][lc] = s;
    }
    __syncthreads();

    // ---- PHASE C ----
    if (tid < 256) {
        int rr = tid >> 3, jj = tid & 7;
        int jh = cb * 8 + jj;
        float i_ = bias[jh]        + st[rr][jj];
        float f_ = bias[jh + 512]  + st[rr][jj + 8];
        float g_ = bias[jh + 1024] + st[rr][jj + 16];
        float o_ = bias[jh + 1536] + st[rr][jj + 24];
        int idx = rr * HIDD + jh;
        float ci = cst[idx];
        float cn = sigmoidf_(f_) * ci + sigmoidf_(i_) * tanhf(g_);
        float hn = sigmoidf_(o_) * tanhf(cn);
        cst[idx] = cn;
        hbf[idx] = f2bf(hn);
        hf8[idx] = f2e4m3(hn * SH);
    }
}

// ---------------------------------------------------------------------------
// logits_fp8b: 250 blocks x 512 thr, 2 blocks/CU (4 waves/SIMD). Wave wv:
// col-group p = wv&3 (g = blk*4+p), K-half kh = wv>>2 (8 paired-kt tiles =
// 16 MFMAs as 2 chains). wot loaded as ulonglong2 (16B/lane). K-halves
// combined via LDS sacc[4][64][17]; kh==0 waves run the R13-proven epilogue;
// tid<32 merges 4 groups -> part slot blockIdx.
// C/D layout: col=lane&31, row=(reg&3)+8*(reg>>2)+4*(lane>>5).
// ---------------------------------------------------------------------------
__global__ __launch_bounds__(512, 4) void logits_fp8b_kernel(
    const i64* __restrict__ wot8, const unsigned char* __restrict__ h_f8,
    const float* __restrict__ bo, const int* __restrict__ labels,
    float* __restrict__ part, int t) {
    __shared__ __align__(16) i64 s_h[2048];    // 16 KB paired frag-order
    __shared__ float sacc[4][64][17];          // 17.4 KB K-half partials
    __shared__ int s_lab[32];
    __shared__ float s_pm[4][32], s_ps[4][32], s_pl[4][32], s_pst[4][32];
    __shared__ int s_pi[4][32];
    int tid = threadIdx.x;
    int lane = tid & 63, wv = tid >> 6;
    int p = wv & 3, kh = wv >> 2;

    // stage h_f8 in paired layout: idx = (kt>>1)*128 + ln*2 + (kt&1)
    for (int f = tid; f < 2048; f += 512) {
        int kt = f >> 6, ln = f & 63;
        int row = ln & 31, kb = kt * 16 + ((ln >> 5) << 3);
        s_h[(kt >> 1) * 128 + ln * 2 + (kt & 1)] = *(const i64*)&h_f8[row * 512 + kb];
    }
    if (tid < 32) s_lab[tid] = labels[tid * TLEN + t];
    __syncthreads();

    int g = blockIdx.x * 4 + p;                 // col-group 0..999
    const ulonglong2* wp16 = (const ulonglong2*)(wot8 + (size_t)g * 2048) + lane;
    const ulonglong2* sh16 = (const ulonglong2*)s_h + lane;

    f32x16 acc0 = {}, acc1 = {};
    #pragma unroll
    for (int i = 0; i < 8; ++i) {
        int ktp = kh * 8 + i;
        ulonglong2 ah = sh16[ktp * 64];
        ulonglong2 wq = wp16[ktp * 64];
        acc0 = __builtin_amdgcn_mfma_f32_32x32x16_fp8_fp8(
            (i64)ah.x, (i64)wq.x, acc0, 0, 0, 0);
        acc1 = __builtin_amdgcn_mfma_f32_32x32x16_fp8_fp8(
            (i64)ah.y, (i64)wq.y, acc1, 0, 0, 0);
    }

    if (kh == 1) {
        #pragma unroll
        for (int reg = 0; reg < 16; ++reg)
            sacc[p][lane][reg] = acc0[reg] + acc1[reg];
    }
    __syncthreads();

    if (kh == 0) {
        int half = lane >> 5;
        int colw = lane & 31;
        int col = g * 32 + colw;
        float bq = bo[col];
        #pragma unroll
        for (int reg = 0; reg < 16; ++reg) {
            int row = (reg & 3) + 8 * (reg >> 2) + 4 * half;
            float v = (acc0[reg] + acc1[reg] + sacc[p][lane][reg]) * INV_SWH + bq;
            float m = v; int mi = col;
            #pragma unroll
            for (int d = 1; d < 32; d <<= 1) {
                float om = __shfl_xor(m, d);
                int omi = __shfl_xor(mi, d);
                if (om > m || (om == m && omi < mi)) { m = om; mi = omi; }
            }
            float e = expf(v - m), ssum = e;
            #pragma unroll
            for (int d = 1; d < 32; d <<= 1) ssum += __shfl_xor(ssum, d);
            int labc = s_lab[row];
            float lv = __shfl(v, (labc & 31) + (half << 5));
            if ((labc >> 5) != g) lv = -INFINITY;
            float sv = __shfl(v, 2 + (half << 5));   // STOP = 2
            if (g != 0) sv = -INFINITY;
            if (colw == 0) {
                s_pm[p][row] = m; s_ps[p][row] = ssum; s_pi[p][row] = mi;
                s_pl[p][row] = lv; s_pst[p][row] = sv;
            }
        }
    }
    __syncthreads();

    if (tid < 32) {
        int row = tid;
        float M = s_pm[0][row], S = s_ps[0][row];
        int MI = s_pi[0][row];
        float L = s_pl[0][row], ST = s_pst[0][row];
        #pragma unroll
        for (int w = 1; w < 4; ++w) {
            float pm = s_pm[w][row], ps = s_ps[w][row];
            int pi = s_pi[w][row];
            float nM = fmaxf(M, pm);
            S = S * expf(M - nM) + ps * expf(pm - nM);
            if (pm > M || (pm == M && pi < MI)) MI = pi;
            M = nM;
            L = fmaxf(L, s_pl[w][row]);
            ST = fmaxf(ST, s_pst[w][row]);
        }
        int e0 = row * 256 + blockIdx.x;
        part[e0] = M;
        part[PSTRIDE + e0] = S;
        part[2 * PSTRIDE + e0] = __int_as_float(MI);
        part[3 * PSTRIDE + e0] = L;
        part[4 * PSTRIDE + e0] = ST;
    }
}

// ---------------------------------------------------------------------------
// finalize5 (R13-verified): STOP-step CE; out = (ce_acc + final)/32
// ---------------------------------------------------------------------------
__global__ __launch_bounds__(256) void finalize5_kernel(
    const float* __restrict__ part, const float* __restrict__ ce_acc,
    float* __restrict__ out) {
    __shared__ float s_ce[32];
    int tid = threadIdx.x;
    int row = tid >> 3, slot = tid & 7;
    float M = -3.0e38f, S = 0.f, ST = -INFINITY;
    for (int ib = slot; ib < NLB; ib += 8) {
        int e = row * 256 + ib;
        float pm = part[e], ps = part[PSTRIDE + e];
        float nM = fmaxf(M, pm);
        S = S * expf(M - nM) + ps * expf(pm - nM);
        M = nM;
        ST = fmaxf(ST, part[4 * PSTRIDE + e]);
    }
    #pragma unroll
    for (int d = 1; d < 8; d <<= 1) {
        float oM = __shfl_xor(M, d), oS = __shfl_xor(S, d);
        float nM = fmaxf(M, oM);
        S = S * expf(M - nM) + oS * expf(oM - nM);
        M = nM;
        ST = fmaxf(ST, __shfl_xor(ST, d));
    }
    if (slot == 0) s_ce[row] = ce_acc[row] + (M + logf(S)) - ST;
    __syncthreads();
    if (tid == 0) {
        float tot = 0.f;
        for (int r = 0; r < 32; ++r) tot += s_ce[r];
        *out = tot / 32.f;
    }
}

// ===========================================================================
extern "C" void kernel_launch(void* const* d_in, const int* in_sizes, int n_in,
                              void* d_out, int out_size, void* d_ws, size_t ws_size,
                              hipStream_t stream) {
    const float* x      = (const float*)d_in[0];
    const int*   labels = (const int*)  d_in[1];
    const void*  coin   =               d_in[2];
    const float* emb    = (const float*)d_in[3];
    const float* Wi     = (const float*)d_in[4];
    const float* Wh     = (const float*)d_in[5];
    const float* b      = (const float*)d_in[6];
    const float* Wo     = (const float*)d_in[7];
    const float* bo     = (const float*)d_in[8];

    float* ws     = (float*)d_ws;
    float* cst    = ws;                        // 16384
    unsigned short* h_bf = (unsigned short*)(ws + 16384);   // 8192 floats
    unsigned char*  h_f8 = (unsigned char*)(ws + 24576);    // 4096 floats
    float* part   = ws + 28672;                // 5*8192 = 40960
    float* ce_acc = ws + 69632;                // 32
    int*   flag   = (int*)(ws + 69664);        // 1 (+pad)
    unsigned short* wcell = (unsigned short*)(ws + 69696);  // 1048576 floats
    i64*   wot8   = (i64*)(ws + 69696 + 1048576);           // 4096000 floats
    unsigned short* embbf = (unsigned short*)(ws + 69696 + 1048576 + 4096000); // 8192000 floats
    float* outp   = (float*)d_out;

    size_t need_emb = (size_t)(69696 + 1048576 + 4096000 + 8192000) * 4;
    const unsigned short* embbf_use = (ws_size >= need_emb) ? embbf : (const unsigned short*)0;

    wot8_prep_kernel<<<NGRP, 256, 0, stream>>>(Wo, wot8);
    wcell_prep_kernel<<<128, 256, 0, stream>>>(Wi, Wh, wcell);
    if (embbf_use)
        emb_prep_kernel<<<VOCABSZ * EMBD / 2048, 256, 0, stream>>>(emb, embbf);
    init7_kernel<<<64, 256, 0, stream>>>(x, coin, cst, h_bf, h_f8, ce_acc, flag);

    for (int t = 0; t < 33; ++t) {
        int tt = (t < 32) ? t : 0;
        cell_mfma4_kernel<<<64, 1024, 0, stream>>>(emb, embbf_use, labels, coin,
                                                   flag, wcell, b, cst, h_bf,
                                                   h_f8, part, ce_acc, t);
        logits_fp8b_kernel<<<NLB, 512, 0, stream>>>(wot8, h_f8, bo, labels,
                                                    part, tt);
    }
    finalize5_kernel<<<1, 256, 0, stream>>>(part, ce_acc, outp);
}